// Round 1
// baseline (948.385 us; speedup 1.0000x reference)
//
#include <hip/hip_runtime.h>
#include <math.h>

// Problem constants (derived at launch from in_sizes where possible)
// N=50000, E=800000, G=512, IN=128, HID=32, H1=8, H2=4, OUT=128, D1=256, D2=128

// ---------------------------------------------------------------------------
// Wave-level sum over all 64 lanes
static __device__ __forceinline__ float wave_sum(float v) {
#pragma unroll
  for (int off = 1; off < 64; off <<= 1) v += __shfl_xor(v, off, 64);
  return v;
}

// ---------------------------------------------------------------------------
// fp32 tiled GEMM: C[M,N] = A[M,K] @ B[K,N] (+ bias[N] if bias != nullptr)
// 64x64 tile, 256 threads, 4x4 register blocking, BK=16. N % 64 == 0, K % 16 == 0.
__global__ __launch_bounds__(256) void gemm_bias_kernel(
    const float* __restrict__ A, const float* __restrict__ B,
    const float* __restrict__ bias, float* __restrict__ C,
    int M, int N, int K) {
  __shared__ float As[16][68];  // [k][m], padded
  __shared__ float Bs[16][64];  // [k][n]
  const int tid = threadIdx.x;
  const int tx = tid & 15;      // 0..15 -> col group
  const int ty = tid >> 4;      // 0..15 -> row group
  const int row0 = blockIdx.y * 64;
  const int col0 = blockIdx.x * 64;

  float acc[4][4];
#pragma unroll
  for (int i = 0; i < 4; i++)
#pragma unroll
    for (int j = 0; j < 4; j++) acc[i][j] = 0.f;

  for (int k0 = 0; k0 < K; k0 += 16) {
    // load A tile: thread -> row = tid>>2 (0..63), k = (tid&3)*4, float4, store transposed
    {
      const int ar = tid >> 2;
      const int ak = (tid & 3) * 4;
      const int grow = row0 + ar;
      float4 av = make_float4(0.f, 0.f, 0.f, 0.f);
      if (grow < M) av = *(const float4*)&A[(size_t)grow * K + k0 + ak];
      As[ak + 0][ar] = av.x;
      As[ak + 1][ar] = av.y;
      As[ak + 2][ar] = av.z;
      As[ak + 3][ar] = av.w;
    }
    // load B tile: thread -> k = tid>>4 (0..15), col = (tid&15)*4, float4
    {
      const int brow = tid >> 4;
      const int bcol = (tid & 15) * 4;
      float4 bv = *(const float4*)&B[(size_t)(k0 + brow) * N + col0 + bcol];
      *(float4*)&Bs[brow][bcol] = bv;
    }
    __syncthreads();
#pragma unroll
    for (int kk = 0; kk < 16; kk++) {
      const float4 a = *(const float4*)&As[kk][ty * 4];
      const float4 b = *(const float4*)&Bs[kk][tx * 4];
      const float ar[4] = {a.x, a.y, a.z, a.w};
      const float br[4] = {b.x, b.y, b.z, b.w};
#pragma unroll
      for (int i = 0; i < 4; i++)
#pragma unroll
        for (int j = 0; j < 4; j++) acc[i][j] += ar[i] * br[j];
    }
    __syncthreads();
  }

  float4 bv = make_float4(0.f, 0.f, 0.f, 0.f);
  if (bias) bv = *(const float4*)&bias[col0 + tx * 4];
#pragma unroll
  for (int i = 0; i < 4; i++) {
    const int r = row0 + ty * 4 + i;
    if (r < M) {
      float4 o;
      o.x = acc[i][0] + bv.x;
      o.y = acc[i][1] + bv.y;
      o.z = acc[i][2] + bv.z;
      o.w = acc[i][3] + bv.w;
      *(float4*)&C[(size_t)r * N + col0 + tx * 4] = o;
    }
  }
}

// ---------------------------------------------------------------------------
// Attention logits: asrc[n,h] = sum_c h[n,h*C+c]*a_src[h,c]; same for adst.
// One wave per node (4 waves per 256-thread block). VEC = H*C/64.
template <int H, int C, int VEC>
__global__ __launch_bounds__(256) void attn_kernel(
    const float* __restrict__ hfeat, const float* __restrict__ a_src,
    const float* __restrict__ a_dst, float* __restrict__ asrc,
    float* __restrict__ adst, int N) {
  const int DOUT = H * C;
  const int wave = threadIdx.x >> 6;
  const int lane = threadIdx.x & 63;
  const int n = blockIdx.x * 4 + wave;
  if (n >= N) return;

  const float* hr = &hfeat[(size_t)n * DOUT + lane * VEC];
  const float* sr = &a_src[lane * VEC];
  const float* dr = &a_dst[lane * VEC];
  float hv[VEC], sv[VEC], dv[VEC];
  if constexpr (VEC == 4) {
    float4 t = *(const float4*)hr; hv[0] = t.x; hv[1] = t.y; hv[2] = t.z; hv[3] = t.w;
    float4 s = *(const float4*)sr; sv[0] = s.x; sv[1] = s.y; sv[2] = s.z; sv[3] = s.w;
    float4 d = *(const float4*)dr; dv[0] = d.x; dv[1] = d.y; dv[2] = d.z; dv[3] = d.w;
  } else {
    float2 t = *(const float2*)hr; hv[0] = t.x; hv[1] = t.y;
    float2 s = *(const float2*)sr; sv[0] = s.x; sv[1] = s.y;
    float2 d = *(const float2*)dr; dv[0] = d.x; dv[1] = d.y;
  }
  float ps = 0.f, pd = 0.f;
#pragma unroll
  for (int i = 0; i < VEC; i++) {
    ps += hv[i] * sv[i];
    pd += hv[i] * dv[i];
  }
  const int L = C / VEC;  // lanes per head
#pragma unroll
  for (int off = 1; off < L; off <<= 1) {
    ps += __shfl_xor(ps, off, 64);
    pd += __shfl_xor(pd, off, 64);
  }
  if ((lane % L) == 0) {
    const int hh = lane / L;
    asrc[n * H + hh] = ps;
    adst[n * H + hh] = pd;
  }
}

// ---------------------------------------------------------------------------
// GAT aggregate + bias + LayerNorm + residual + ELU, one wave per dst node.
// io holds proj (= x@pw+pb) on entry and the layer output on exit.
template <int H, int C, int VEC>
__global__ __launch_bounds__(256) void gat_agg_kernel(
    const float* __restrict__ hfeat, const float* __restrict__ asrc,
    const float* __restrict__ adst, const int* __restrict__ rowptr,
    const int* __restrict__ col, const float* __restrict__ bias,
    const float* __restrict__ gamma, const float* __restrict__ beta,
    float* __restrict__ io, int N) {
  const int DOUT = H * C;
  const int wave = threadIdx.x >> 6;
  const int lane = threadIdx.x & 63;
  const int n = blockIdx.x * 4 + wave;
  if (n >= N) return;

  const int start = rowptr[n];
  const int deg = rowptr[n + 1] - start;

  float adl[H];
#pragma unroll
  for (int hh = 0; hh < H; hh++) adl[hh] = adst[n * H + hh];

  // Phase 1: softmax denominators per head (no max-shift: logits are O(1))
  float se[H];
#pragma unroll
  for (int hh = 0; hh < H; hh++) se[hh] = 0.f;
  for (int j = lane; j <= deg; j += 64) {  // j == deg is the self-loop
    const int src = (j < deg) ? col[start + j] : n;
#pragma unroll
    for (int hh = 0; hh < H; hh++) {
      float e = asrc[src * H + hh] + adl[hh];
      e = (e > 0.f) ? e : 0.2f * e;
      se[hh] += __expf(e);
    }
  }
#pragma unroll
  for (int hh = 0; hh < H; hh++) se[hh] = wave_sum(se[hh]) + 1e-16f;

  // Phase 2: alpha-weighted aggregation, whole wave per edge (coalesced row read)
  const int myh = (lane * VEC) / C;
  float acc[VEC];
#pragma unroll
  for (int i = 0; i < VEC; i++) acc[i] = 0.f;
  int src_next = (deg > 0) ? col[start] : n;
  for (int j = 0; j <= deg; j++) {
    const int src = src_next;
    src_next = (j + 1 < deg) ? col[start + j + 1] : n;
    float e = asrc[src * H + myh] + adl[myh];
    e = (e > 0.f) ? e : 0.2f * e;
    const float alpha = __expf(e) / se[myh];
    const float* hr = &hfeat[(size_t)src * DOUT + lane * VEC];
    float hv[VEC];
    if constexpr (VEC == 4) {
      float4 t = *(const float4*)hr; hv[0] = t.x; hv[1] = t.y; hv[2] = t.z; hv[3] = t.w;
    } else {
      float2 t = *(const float2*)hr; hv[0] = t.x; hv[1] = t.y;
    }
#pragma unroll
    for (int i = 0; i < VEC; i++) acc[i] += hv[i] * alpha;
  }

  // bias, LayerNorm over DOUT, + residual proj, ELU
  float m = 0.f;
#pragma unroll
  for (int i = 0; i < VEC; i++) {
    acc[i] += bias[lane * VEC + i];
    m += acc[i];
  }
  m = wave_sum(m) / (float)DOUT;
  float vs = 0.f;
#pragma unroll
  for (int i = 0; i < VEC; i++) {
    const float d = acc[i] - m;
    vs += d * d;
  }
  vs = wave_sum(vs) / (float)DOUT;
  const float rstd = rsqrtf(vs + 1e-5f);

  float* iop = &io[(size_t)n * DOUT + lane * VEC];
#pragma unroll
  for (int i = 0; i < VEC; i++) {
    const int c = lane * VEC + i;
    float v = (acc[i] - m) * rstd * gamma[c] + beta[c] + iop[i];
    iop[i] = (v > 0.f) ? v : expm1f(v);
  }
}

// ---------------------------------------------------------------------------
// CSR build
__global__ void hist_kernel(const int* __restrict__ dst, int* __restrict__ cnt, int E) {
  const int e = blockIdx.x * 256 + threadIdx.x;
  if (e < E) atomicAdd(&cnt[dst[e]], 1);
}

__global__ __launch_bounds__(1024) void scan_kernel(const int* __restrict__ cnt,
                                                    int* __restrict__ rowptr, int N) {
  __shared__ int smem[1024];
  __shared__ int carry;
  const int tid = threadIdx.x;
  if (tid == 0) carry = 0;
  __syncthreads();
  for (int base = 0; base < N; base += 1024) {
    const int i = base + tid;
    const int v = (i < N) ? cnt[i] : 0;
    smem[tid] = v;
    __syncthreads();
    for (int off = 1; off < 1024; off <<= 1) {
      const int t = (tid >= off) ? smem[tid - off] : 0;
      __syncthreads();
      smem[tid] += t;
      __syncthreads();
    }
    if (i < N) rowptr[i] = carry + smem[tid] - v;  // exclusive
    __syncthreads();
    if (tid == 1023) carry += smem[1023];
    __syncthreads();
  }
  if (tid == 0) rowptr[N] = carry;
}

__global__ void copy_int_kernel(const int* __restrict__ a, int* __restrict__ b, int n) {
  const int i = blockIdx.x * 256 + threadIdx.x;
  if (i < n) b[i] = a[i];
}

__global__ void scatter_kernel(const int* __restrict__ src, const int* __restrict__ dst,
                               int* __restrict__ cursor, int* __restrict__ col, int E) {
  const int e = blockIdx.x * 256 + threadIdx.x;
  if (e < E) {
    const int p = atomicAdd(&cursor[dst[e]], 1);
    col[p] = src[e];
  }
}

// ---------------------------------------------------------------------------
// Global mean pool per graph (batch is sorted): one block per graph,
// binary-search the node range, column-parallel coalesced mean.
__global__ __launch_bounds__(128) void pool_kernel(const float* __restrict__ h3,
                                                   const int* __restrict__ batch,
                                                   float* __restrict__ out, int N) {
  __shared__ int sse[2];
  const int g = blockIdx.x;
  if (threadIdx.x == 0) {
    int lo = 0, hi = N;
    while (lo < hi) { const int mid = (lo + hi) >> 1; if (batch[mid] < g) lo = mid + 1; else hi = mid; }
    sse[0] = lo;
    lo = 0; hi = N;
    while (lo < hi) { const int mid = (lo + hi) >> 1; if (batch[mid] < g + 1) lo = mid + 1; else hi = mid; }
    sse[1] = lo;
  }
  __syncthreads();
  const int s = sse[0], e = sse[1];
  float sum = 0.f;
  for (int r = s; r < e; r++) sum += h3[(size_t)r * 128 + threadIdx.x];
  out[g * 128 + threadIdx.x] = (e > s) ? sum / (float)(e - s) : 0.f;
}

// ---------------------------------------------------------------------------
extern "C" void kernel_launch(void* const* d_in, const int* in_sizes, int n_in,
                              void* d_out, int out_size, void* d_ws, size_t ws_size,
                              hipStream_t stream) {
  const float* x      = (const float*)d_in[0];
  const int* edge_idx = (const int*)d_in[1];
  const int* batch    = (const int*)d_in[2];
  const float* W1     = (const float*)d_in[3];
  const float* a_src1 = (const float*)d_in[4];
  const float* a_dst1 = (const float*)d_in[5];
  const float* b1     = (const float*)d_in[6];
  const float* g1     = (const float*)d_in[7];
  const float* be1    = (const float*)d_in[8];
  const float* pw1    = (const float*)d_in[9];
  const float* pb1    = (const float*)d_in[10];
  const float* W2     = (const float*)d_in[11];
  const float* a_src2 = (const float*)d_in[12];
  const float* a_dst2 = (const float*)d_in[13];
  const float* b2     = (const float*)d_in[14];
  const float* g2     = (const float*)d_in[15];
  const float* be2    = (const float*)d_in[16];
  const float* pw2    = (const float*)d_in[17];
  const float* pb2    = (const float*)d_in[18];
  const float* W3     = (const float*)d_in[19];
  const float* a_src3 = (const float*)d_in[20];
  const float* a_dst3 = (const float*)d_in[21];
  const float* b3     = (const float*)d_in[22];
  const float* g3     = (const float*)d_in[23];
  const float* be3    = (const float*)d_in[24];
  const float* pw3    = (const float*)d_in[25];
  const float* pb3    = (const float*)d_in[26];

  const int N = in_sizes[0] / 128;   // 50000
  const int E = in_sizes[1] / 2;     // 800000
  const int G = out_size / 128;      // 512

  // workspace layout (256B-aligned)
  size_t off = 0;
  auto alloc = [&](size_t bytes) {
    size_t r = off;
    off += (bytes + 255) & ~(size_t)255;
    return r;
  };
  char* ws = (char*)d_ws;
  float* bufA   = (float*)(ws + alloc((size_t)N * 256 * 4));  // 51.2 MB
  float* bufH   = (float*)(ws + alloc((size_t)N * 256 * 4));  // 51.2 MB
  float* bufB   = (float*)(ws + alloc((size_t)N * 128 * 4));  // 25.6 MB
  float* asrcB  = (float*)(ws + alloc((size_t)N * 8 * 4));
  float* adstB  = (float*)(ws + alloc((size_t)N * 8 * 4));
  int*   rowptr = (int*)  (ws + alloc((size_t)(N + 1) * 4));
  int*   cnt    = (int*)  (ws + alloc((size_t)N * 4));
  int*   cursor = (int*)  (ws + alloc((size_t)N * 4));
  int*   col    = (int*)  (ws + alloc((size_t)E * 4));
  (void)ws_size; (void)n_in;

  const int EB = (E + 255) / 256;
  const int NB = (N + 255) / 256;
  const int NW = (N + 3) / 4;  // one wave per node, 4 waves/block

  // ---- CSR build (dst-sorted adjacency), reused by all 3 layers ----
  hipMemsetAsync(cnt, 0, (size_t)N * 4, stream);
  hist_kernel<<<EB, 256, 0, stream>>>(edge_idx + E, cnt, E);
  scan_kernel<<<1, 1024, 0, stream>>>(cnt, rowptr, N);
  copy_int_kernel<<<NB, 256, 0, stream>>>(rowptr, cursor, N);
  scatter_kernel<<<EB, 256, 0, stream>>>(edge_idx, edge_idx + E, cursor, col, E);

  // ---- Layer 1: IN=128 -> 8 heads x 32 = 256 ----
  gemm_bias_kernel<<<dim3(256 / 64, (N + 63) / 64), 256, 0, stream>>>(x, W1, nullptr, bufH, N, 256, 128);
  gemm_bias_kernel<<<dim3(256 / 64, (N + 63) / 64), 256, 0, stream>>>(x, pw1, pb1, bufA, N, 256, 128);
  attn_kernel<8, 32, 4><<<NW, 256, 0, stream>>>(bufH, a_src1, a_dst1, asrcB, adstB, N);
  gat_agg_kernel<8, 32, 4><<<NW, 256, 0, stream>>>(bufH, asrcB, adstB, rowptr, col, b1, g1, be1, bufA, N);
  // bufA = h1 [N,256]

  // ---- Layer 2: 256 -> 4 heads x 32 = 128 ----
  gemm_bias_kernel<<<dim3(128 / 64, (N + 63) / 64), 256, 0, stream>>>(bufA, W2, nullptr, bufH, N, 128, 256);
  gemm_bias_kernel<<<dim3(128 / 64, (N + 63) / 64), 256, 0, stream>>>(bufA, pw2, pb2, bufB, N, 128, 256);
  attn_kernel<4, 32, 2><<<NW, 256, 0, stream>>>(bufH, a_src2, a_dst2, asrcB, adstB, N);
  gat_agg_kernel<4, 32, 2><<<NW, 256, 0, stream>>>(bufH, asrcB, adstB, rowptr, col, b2, g2, be2, bufB, N);
  // bufB = h2 [N,128]

  // ---- Layer 3: 128 -> 1 head x 128 (concat=False, 1 head -> identity mean) ----
  gemm_bias_kernel<<<dim3(128 / 64, (N + 63) / 64), 256, 0, stream>>>(bufB, W3, nullptr, bufH, N, 128, 128);
  gemm_bias_kernel<<<dim3(128 / 64, (N + 63) / 64), 256, 0, stream>>>(bufB, pw3, pb3, bufA, N, 128, 128);
  attn_kernel<1, 128, 2><<<NW, 256, 0, stream>>>(bufH, a_src3, a_dst3, asrcB, adstB, N);
  gat_agg_kernel<1, 128, 2><<<NW, 256, 0, stream>>>(bufH, asrcB, adstB, rowptr, col, b3, g3, be3, bufA, N);
  // bufA = h3 [N,128]

  // ---- Global mean pool per graph ----
  pool_kernel<<<G, 128, 0, stream>>>(bufA, batch, (float*)d_out, N);
}

// Round 2
// 775.885 us; speedup vs baseline: 1.2223x; 1.2223x over previous
//
#include <hip/hip_runtime.h>
#include <math.h>

// N=50000, E=800000, G=512, IN=128, HID=32, H1=8, H2=4, OUT=128, D1=256, D2=128

typedef __bf16 bf16x8 __attribute__((ext_vector_type(8)));
typedef float f32x4 __attribute__((ext_vector_type(4)));

static __device__ __forceinline__ float bf2f(unsigned short u) {
  union { unsigned int i; float f; } c;
  c.i = ((unsigned int)u) << 16;
  return c.f;
}
static __device__ __forceinline__ unsigned short f2bf(float f) {
  __bf16 b = (__bf16)f;
  return __builtin_bit_cast(unsigned short, b);
}
static __device__ __forceinline__ float wave_sum(float v) {
#pragma unroll
  for (int off = 1; off < 64; off <<= 1) v += __shfl_xor(v, off, 64);
  return v;
}

// ---------------------------------------------------------------------------
// bf16 MFMA GEMM: C[M64,Ncols] = A[M64,K] @ B[K,Ncols] (+bias). M64 % 64 == 0.
// Block = 4 waves in 2x2; each wave computes 32x32 via 2x2 MFMA 16x16x32 tiles.
// A is row-major bf16 (direct fragment loads, 16B/lane). Bp is pre-repacked
// into B-fragment order: idx = ((nt*(K/32)+kb)*64+lane)*8+j holds
// B[kb*32 + (lane>>4)*8 + j][nt*16 + (lane&15)].
template <int K, typename OutT>
__global__ __launch_bounds__(256) void mfma_gemm_kernel(
    const unsigned short* __restrict__ A, const unsigned short* __restrict__ Bp,
    const float* __restrict__ bias, OutT* __restrict__ C, int Ncols) {
  const int lane = threadIdx.x & 63;
  const int w = threadIdx.x >> 6;
  const int ml = lane & 15, kq = lane >> 4;
  const int row0 = blockIdx.y * 64 + (w >> 1) * 32;
  const int colt0 = blockIdx.x * 4 + (w & 1) * 2;
  constexpr int KB = K / 32;

  f32x4 acc00 = {}, acc01 = {}, acc10 = {}, acc11 = {};
  const unsigned short* a0 = A + (size_t)(row0 + ml) * K + kq * 8;
  const unsigned short* b0 = Bp + ((size_t)colt0 * KB * 64 + lane) * 8;
#pragma unroll
  for (int kb = 0; kb < KB; kb++) {
    bf16x8 af0 = __builtin_bit_cast(bf16x8, *(const uint4*)(a0 + kb * 32));
    bf16x8 af1 = __builtin_bit_cast(bf16x8, *(const uint4*)(a0 + 16 * K + kb * 32));
    bf16x8 bf0 = __builtin_bit_cast(bf16x8, *(const uint4*)(b0 + (size_t)kb * 512));
    bf16x8 bf1 = __builtin_bit_cast(bf16x8, *(const uint4*)(b0 + (size_t)(KB + kb) * 512));
    acc00 = __builtin_amdgcn_mfma_f32_16x16x32_bf16(af0, bf0, acc00, 0, 0, 0);
    acc01 = __builtin_amdgcn_mfma_f32_16x16x32_bf16(af0, bf1, acc01, 0, 0, 0);
    acc10 = __builtin_amdgcn_mfma_f32_16x16x32_bf16(af1, bf0, acc10, 0, 0, 0);
    acc11 = __builtin_amdgcn_mfma_f32_16x16x32_bf16(af1, bf1, acc11, 0, 0, 0);
  }
  const int c0 = colt0 * 16 + ml, c1 = c0 + 16;
  float bias0 = 0.f, bias1 = 0.f;
  if (bias) { bias0 = bias[c0]; bias1 = bias[c1]; }
#pragma unroll
  for (int r = 0; r < 4; r++) {
    const size_t rA = (size_t)(row0 + kq * 4 + r);
    const size_t rB = rA + 16;
    float v00 = acc00[r] + bias0, v01 = acc01[r] + bias1;
    float v10 = acc10[r] + bias0, v11 = acc11[r] + bias1;
    if constexpr (sizeof(OutT) == 2) {
      C[rA * Ncols + c0] = f2bf(v00);
      C[rA * Ncols + c1] = f2bf(v01);
      C[rB * Ncols + c0] = f2bf(v10);
      C[rB * Ncols + c1] = f2bf(v11);
    } else {
      C[rA * Ncols + c0] = v00;
      C[rA * Ncols + c1] = v01;
      C[rB * Ncols + c0] = v10;
      C[rB * Ncols + c1] = v11;
    }
  }
}

// Repack fp32 weight [K][Ncols] into bf16 B-fragment order.
__global__ void repack_b_kernel(const float* __restrict__ B, unsigned short* __restrict__ Bp,
                                int K, int Ncols) {
  const int idx = blockIdx.x * 256 + threadIdx.x;
  const int KB = K >> 5;
  const int total = (Ncols >> 4) * KB * 64;
  if (idx >= total) return;
  const int lane = idx & 63;
  const int kb = (idx >> 6) % KB;
  const int nt = idx / (KB << 6);
  const int ml = lane & 15, kq = lane >> 4;
  unsigned short* dst = Bp + (size_t)idx * 8;
#pragma unroll
  for (int j = 0; j < 8; j++)
    dst[j] = f2bf(B[(size_t)(kb * 32 + kq * 8 + j) * Ncols + nt * 16 + ml]);
}

__global__ void cast_bf16_kernel(const float* __restrict__ src,
                                 unsigned short* __restrict__ dst, int n4) {
  const int i = blockIdx.x * 256 + threadIdx.x;
  if (i >= n4) return;
  float4 v = ((const float4*)src)[i];
  ushort4 o;
  o.x = f2bf(v.x); o.y = f2bf(v.y); o.z = f2bf(v.z); o.w = f2bf(v.w);
  ((ushort4*)dst)[i] = o;
}

// ---------------------------------------------------------------------------
// Attention logits from bf16 features. One wave per node. VEC = H*C/64.
template <int H, int C, int VEC>
__global__ __launch_bounds__(256) void attn_kernel(
    const unsigned short* __restrict__ hfeat, const float* __restrict__ a_src,
    const float* __restrict__ a_dst, float* __restrict__ asrc,
    float* __restrict__ adst, int N) {
  const int DOUT = H * C;
  const int wave = threadIdx.x >> 6;
  const int lane = threadIdx.x & 63;
  const int n = blockIdx.x * 4 + wave;
  if (n >= N) return;

  const unsigned short* hr = &hfeat[(size_t)n * DOUT + lane * VEC];
  float hv[VEC], sv[VEC], dv[VEC];
  if constexpr (VEC == 4) {
    ushort4 t = *(const ushort4*)hr;
    hv[0] = bf2f(t.x); hv[1] = bf2f(t.y); hv[2] = bf2f(t.z); hv[3] = bf2f(t.w);
    float4 s = *(const float4*)&a_src[lane * 4];
    sv[0] = s.x; sv[1] = s.y; sv[2] = s.z; sv[3] = s.w;
    float4 d = *(const float4*)&a_dst[lane * 4];
    dv[0] = d.x; dv[1] = d.y; dv[2] = d.z; dv[3] = d.w;
  } else {
    ushort2 t = *(const ushort2*)hr;
    hv[0] = bf2f(t.x); hv[1] = bf2f(t.y);
    float2 s = *(const float2*)&a_src[lane * 2];
    sv[0] = s.x; sv[1] = s.y;
    float2 d = *(const float2*)&a_dst[lane * 2];
    dv[0] = d.x; dv[1] = d.y;
  }
  float ps = 0.f, pd = 0.f;
#pragma unroll
  for (int i = 0; i < VEC; i++) {
    ps += hv[i] * sv[i];
    pd += hv[i] * dv[i];
  }
  const int L = C / VEC;
#pragma unroll
  for (int off = 1; off < L; off <<= 1) {
    ps += __shfl_xor(ps, off, 64);
    pd += __shfl_xor(pd, off, 64);
  }
  if ((lane % L) == 0) {
    const int hh = lane / L;
    asrc[n * H + hh] = ps;
    adst[n * H + hh] = pd;
  }
}

// ---------------------------------------------------------------------------
// GAT aggregate (bf16 rows) + bias + LayerNorm + fp32 residual + ELU -> bf16 out.
template <int H, int C, int VEC>
__global__ __launch_bounds__(256) void gat_agg_kernel(
    const unsigned short* __restrict__ hfeat, const float* __restrict__ asrc,
    const float* __restrict__ adst, const int* __restrict__ rowptr,
    const int* __restrict__ col, const float* __restrict__ bias,
    const float* __restrict__ gamma, const float* __restrict__ beta,
    const float* __restrict__ proj, unsigned short* __restrict__ out, int N) {
  const int DOUT = H * C;
  const int wave = threadIdx.x >> 6;
  const int lane = threadIdx.x & 63;
  const int n = blockIdx.x * 4 + wave;
  if (n >= N) return;

  const int start = rowptr[n];
  const int deg = rowptr[n + 1] - start;

  float adl[H];
#pragma unroll
  for (int hh = 0; hh < H; hh++) adl[hh] = adst[n * H + hh];

  // Phase 1: softmax denominators (logits are O(1); no max-shift needed)
  float se[H];
#pragma unroll
  for (int hh = 0; hh < H; hh++) se[hh] = 0.f;
  for (int j = lane; j <= deg; j += 64) {  // j == deg is the self-loop
    const int src = (j < deg) ? col[start + j] : n;
#pragma unroll
    for (int hh = 0; hh < H; hh++) {
      float e = asrc[src * H + hh] + adl[hh];
      e = (e > 0.f) ? e : 0.2f * e;
      se[hh] += __expf(e);
    }
  }
#pragma unroll
  for (int hh = 0; hh < H; hh++) se[hh] = wave_sum(se[hh]) + 1e-16f;

  // Phase 2: alpha-weighted aggregation, whole wave per edge (coalesced row read)
  const int myh = (lane * VEC) / C;
  float acc[VEC];
#pragma unroll
  for (int i = 0; i < VEC; i++) acc[i] = 0.f;
  int src_next = (deg > 0) ? col[start] : n;
  for (int j = 0; j <= deg; j++) {
    const int src = src_next;
    src_next = (j + 1 < deg) ? col[start + j + 1] : n;
    float e = asrc[src * H + myh] + adl[myh];
    e = (e > 0.f) ? e : 0.2f * e;
    const float alpha = __expf(e) / se[myh];
    const unsigned short* hr = &hfeat[(size_t)src * DOUT + lane * VEC];
    float hv[VEC];
    if constexpr (VEC == 4) {
      ushort4 t = *(const ushort4*)hr;
      hv[0] = bf2f(t.x); hv[1] = bf2f(t.y); hv[2] = bf2f(t.z); hv[3] = bf2f(t.w);
    } else {
      ushort2 t = *(const ushort2*)hr;
      hv[0] = bf2f(t.x); hv[1] = bf2f(t.y);
    }
#pragma unroll
    for (int i = 0; i < VEC; i++) acc[i] += hv[i] * alpha;
  }

  // bias, LayerNorm over DOUT, + fp32 residual proj, ELU, bf16 store
  float m = 0.f;
#pragma unroll
  for (int i = 0; i < VEC; i++) {
    acc[i] += bias[lane * VEC + i];
    m += acc[i];
  }
  m = wave_sum(m) / (float)DOUT;
  float vs = 0.f;
#pragma unroll
  for (int i = 0; i < VEC; i++) {
    const float d = acc[i] - m;
    vs += d * d;
  }
  vs = wave_sum(vs) / (float)DOUT;
  const float rstd = rsqrtf(vs + 1e-5f);

  const float* pr = &proj[(size_t)n * DOUT + lane * VEC];
  unsigned short* op = &out[(size_t)n * DOUT + lane * VEC];
#pragma unroll
  for (int i = 0; i < VEC; i++) {
    const int c = lane * VEC + i;
    float v = (acc[i] - m) * rstd * gamma[c] + beta[c] + pr[i];
    v = (v > 0.f) ? v : expm1f(v);
    op[i] = f2bf(v);
  }
}

// ---------------------------------------------------------------------------
// CSR build
__global__ void hist_kernel(const int* __restrict__ dst, int* __restrict__ cnt, int E) {
  const int e = blockIdx.x * 256 + threadIdx.x;
  if (e < E) atomicAdd(&cnt[dst[e]], 1);
}

__global__ __launch_bounds__(1024) void scan_kernel(const int* __restrict__ cnt,
                                                    int* __restrict__ rowptr, int N) {
  __shared__ int smem[1024];
  __shared__ int carry;
  const int tid = threadIdx.x;
  if (tid == 0) carry = 0;
  __syncthreads();
  for (int base = 0; base < N; base += 1024) {
    const int i = base + tid;
    const int v = (i < N) ? cnt[i] : 0;
    smem[tid] = v;
    __syncthreads();
    for (int off = 1; off < 1024; off <<= 1) {
      const int t = (tid >= off) ? smem[tid - off] : 0;
      __syncthreads();
      smem[tid] += t;
      __syncthreads();
    }
    if (i < N) rowptr[i] = carry + smem[tid] - v;  // exclusive
    __syncthreads();
    if (tid == 1023) carry += smem[1023];
    __syncthreads();
  }
  if (tid == 0) rowptr[N] = carry;
}

__global__ void copy_int_kernel(const int* __restrict__ a, int* __restrict__ b, int n) {
  const int i = blockIdx.x * 256 + threadIdx.x;
  if (i < n) b[i] = a[i];
}

__global__ void scatter_kernel(const int* __restrict__ src, const int* __restrict__ dst,
                               int* __restrict__ cursor, int* __restrict__ col, int E) {
  const int e = blockIdx.x * 256 + threadIdx.x;
  if (e < E) {
    const int p = atomicAdd(&cursor[dst[e]], 1);
    col[p] = src[e];
  }
}

// ---------------------------------------------------------------------------
// Global mean pool per graph (batch sorted): one block per graph.
__global__ __launch_bounds__(128) void pool_kernel(const unsigned short* __restrict__ h3,
                                                   const int* __restrict__ batch,
                                                   float* __restrict__ out, int N) {
  __shared__ int sse[2];
  const int g = blockIdx.x;
  if (threadIdx.x == 0) {
    int lo = 0, hi = N;
    while (lo < hi) { const int mid = (lo + hi) >> 1; if (batch[mid] < g) lo = mid + 1; else hi = mid; }
    sse[0] = lo;
    lo = 0; hi = N;
    while (lo < hi) { const int mid = (lo + hi) >> 1; if (batch[mid] < g + 1) lo = mid + 1; else hi = mid; }
    sse[1] = lo;
  }
  __syncthreads();
  const int s = sse[0], e = sse[1];
  float sum = 0.f;
  for (int r = s; r < e; r++) sum += bf2f(h3[(size_t)r * 128 + threadIdx.x]);
  out[g * 128 + threadIdx.x] = (e > s) ? sum / (float)(e - s) : 0.f;
}

// ---------------------------------------------------------------------------
extern "C" void kernel_launch(void* const* d_in, const int* in_sizes, int n_in,
                              void* d_out, int out_size, void* d_ws, size_t ws_size,
                              hipStream_t stream) {
  const float* x      = (const float*)d_in[0];
  const int* edge_idx = (const int*)d_in[1];
  const int* batch    = (const int*)d_in[2];
  const float* W1     = (const float*)d_in[3];
  const float* a_src1 = (const float*)d_in[4];
  const float* a_dst1 = (const float*)d_in[5];
  const float* b1     = (const float*)d_in[6];
  const float* g1     = (const float*)d_in[7];
  const float* be1    = (const float*)d_in[8];
  const float* pw1    = (const float*)d_in[9];
  const float* pb1    = (const float*)d_in[10];
  const float* W2     = (const float*)d_in[11];
  const float* a_src2 = (const float*)d_in[12];
  const float* a_dst2 = (const float*)d_in[13];
  const float* b2     = (const float*)d_in[14];
  const float* g2     = (const float*)d_in[15];
  const float* be2    = (const float*)d_in[16];
  const float* pw2    = (const float*)d_in[17];
  const float* pb2    = (const float*)d_in[18];
  const float* W3     = (const float*)d_in[19];
  const float* a_src3 = (const float*)d_in[20];
  const float* a_dst3 = (const float*)d_in[21];
  const float* b3     = (const float*)d_in[22];
  const float* g3     = (const float*)d_in[23];
  const float* be3    = (const float*)d_in[24];
  const float* pw3    = (const float*)d_in[25];
  const float* pb3    = (const float*)d_in[26];

  const int NN = in_sizes[0] / 128;  // 50000
  const int E  = in_sizes[1] / 2;    // 800000
  const int G  = out_size / 128;     // 512
  const int M64 = (NN + 63) & ~63;   // 50048

  // workspace layout (256B-aligned)
  size_t off = 0;
  auto alloc = [&](size_t bytes) {
    size_t r = off;
    off += (bytes + 255) & ~(size_t)255;
    return r;
  };
  char* ws = (char*)d_ws;
  unsigned short* big0 = (unsigned short*)(ws + alloc((size_t)M64 * 256 * 2));  // h1feat / h3feat
  unsigned short* big1 = (unsigned short*)(ws + alloc((size_t)M64 * 256 * 2));  // h1out
  unsigned short* s0   = (unsigned short*)(ws + alloc((size_t)M64 * 128 * 2));  // xb / h2feat / h3out
  unsigned short* s1   = (unsigned short*)(ws + alloc((size_t)M64 * 128 * 2));  // h2out
  float* proj  = (float*)(ws + alloc((size_t)M64 * 256 * 4));                   // fp32 residual (reused)
  float* asrcB = (float*)(ws + alloc((size_t)NN * 8 * 4));
  float* adstB = (float*)(ws + alloc((size_t)NN * 8 * 4));
  int* rowptr  = (int*)(ws + alloc((size_t)(NN + 1) * 4));
  int* cnt     = (int*)(ws + alloc((size_t)NN * 4));
  int* cursor  = (int*)(ws + alloc((size_t)NN * 4));
  int* colb    = (int*)(ws + alloc((size_t)E * 4));
  unsigned short* BpW1 = (unsigned short*)(ws + alloc(128 * 256 * 2));
  unsigned short* BpP1 = (unsigned short*)(ws + alloc(128 * 256 * 2));
  unsigned short* BpW2 = (unsigned short*)(ws + alloc(256 * 128 * 2));
  unsigned short* BpP2 = (unsigned short*)(ws + alloc(256 * 128 * 2));
  unsigned short* BpW3 = (unsigned short*)(ws + alloc(128 * 128 * 2));
  unsigned short* BpP3 = (unsigned short*)(ws + alloc(128 * 128 * 2));
  (void)ws_size; (void)n_in;

  const int EB = (E + 255) / 256;
  const int NB = (NN + 255) / 256;
  const int NW = (NN + 3) / 4;
  const int MB = M64 / 64;
  const int pad = M64 - NN;

  // ---- CSR build (dst-sorted adjacency), reused by all 3 layers ----
  hipMemsetAsync(cnt, 0, (size_t)NN * 4, stream);
  hist_kernel<<<EB, 256, 0, stream>>>(edge_idx + E, cnt, E);
  scan_kernel<<<1, 1024, 0, stream>>>(cnt, rowptr, NN);
  copy_int_kernel<<<NB, 256, 0, stream>>>(rowptr, cursor, NN);
  scatter_kernel<<<EB, 256, 0, stream>>>(edge_idx, edge_idx + E, cursor, colb, E);

  // ---- bf16 cast of x + pad-row zeroing for all GEMM A-inputs ----
  cast_bf16_kernel<<<(NN * 128 / 4 + 255) / 256, 256, 0, stream>>>(x, s0, NN * 128 / 4);
  if (pad) {
    hipMemsetAsync(s0 + (size_t)NN * 128, 0, (size_t)pad * 128 * 2, stream);   // xb pad
    hipMemsetAsync(big1 + (size_t)NN * 256, 0, (size_t)pad * 256 * 2, stream); // h1out pad
    hipMemsetAsync(s1 + (size_t)NN * 128, 0, (size_t)pad * 128 * 2, stream);   // h2out pad
  }

  // ---- weight repacks (tiny) ----
  repack_b_kernel<<<((256 / 16) * (128 / 32) * 64 + 255) / 256, 256, 0, stream>>>(W1, BpW1, 128, 256);
  repack_b_kernel<<<((256 / 16) * (128 / 32) * 64 + 255) / 256, 256, 0, stream>>>(pw1, BpP1, 128, 256);
  repack_b_kernel<<<((128 / 16) * (256 / 32) * 64 + 255) / 256, 256, 0, stream>>>(W2, BpW2, 256, 128);
  repack_b_kernel<<<((128 / 16) * (256 / 32) * 64 + 255) / 256, 256, 0, stream>>>(pw2, BpP2, 256, 128);
  repack_b_kernel<<<((128 / 16) * (128 / 32) * 64 + 255) / 256, 256, 0, stream>>>(W3, BpW3, 128, 128);
  repack_b_kernel<<<((128 / 16) * (128 / 32) * 64 + 255) / 256, 256, 0, stream>>>(pw3, BpP3, 128, 128);

  // ---- Layer 1: 128 -> 8x32 = 256 ----
  mfma_gemm_kernel<128, unsigned short><<<dim3(4, MB), 256, 0, stream>>>(s0, BpW1, nullptr, big0, 256);
  mfma_gemm_kernel<128, float><<<dim3(4, MB), 256, 0, stream>>>(s0, BpP1, pb1, proj, 256);
  attn_kernel<8, 32, 4><<<NW, 256, 0, stream>>>(big0, a_src1, a_dst1, asrcB, adstB, NN);
  gat_agg_kernel<8, 32, 4><<<NW, 256, 0, stream>>>(big0, asrcB, adstB, rowptr, colb, b1, g1, be1, proj, big1, NN);
  // big1 = h1 (bf16)

  // ---- Layer 2: 256 -> 4x32 = 128 ----
  mfma_gemm_kernel<256, unsigned short><<<dim3(2, MB), 256, 0, stream>>>(big1, BpW2, nullptr, s0, 128);
  mfma_gemm_kernel<256, float><<<dim3(2, MB), 256, 0, stream>>>(big1, BpP2, pb2, proj, 128);
  attn_kernel<4, 32, 2><<<NW, 256, 0, stream>>>(s0, a_src2, a_dst2, asrcB, adstB, NN);
  gat_agg_kernel<4, 32, 2><<<NW, 256, 0, stream>>>(s0, asrcB, adstB, rowptr, colb, b2, g2, be2, proj, s1, NN);
  // s1 = h2 (bf16)

  // ---- Layer 3: 128 -> 1x128, concat=False (1 head -> identity mean) ----
  mfma_gemm_kernel<128, unsigned short><<<dim3(2, MB), 256, 0, stream>>>(s1, BpW3, nullptr, big0, 128);
  mfma_gemm_kernel<128, float><<<dim3(2, MB), 256, 0, stream>>>(s1, BpP3, pb3, proj, 128);
  attn_kernel<1, 128, 2><<<NW, 256, 0, stream>>>(big0, a_src3, a_dst3, asrcB, adstB, NN);
  gat_agg_kernel<1, 128, 2><<<NW, 256, 0, stream>>>(big0, asrcB, adstB, rowptr, colb, b3, g3, be3, proj, s0, NN);
  // s0 = h3 (bf16)

  // ---- Global mean pool per graph ----
  pool_kernel<<<G, 128, 0, stream>>>(s0, batch, (float*)d_out, NN);
}

// Round 3
// 709.364 us; speedup vs baseline: 1.3370x; 1.0938x over previous
//
#include <hip/hip_runtime.h>
#include <math.h>
#include <type_traits>

// N=50000, E=800000, G=512, IN=128, HID=32, H1=8, H2=4, OUT=128, D1=256, D2=128

typedef __bf16 bf16x8 __attribute__((ext_vector_type(8)));
typedef float f32x4 __attribute__((ext_vector_type(4)));

static __device__ __forceinline__ float bf2f(unsigned short u) {
  union { unsigned int i; float f; } c;
  c.i = ((unsigned int)u) << 16;
  return c.f;
}
static __device__ __forceinline__ unsigned short f2bf(float f) {
  __bf16 b = (__bf16)f;
  return __builtin_bit_cast(unsigned short, b);
}
static __device__ __forceinline__ float wave_sum(float v) {
#pragma unroll
  for (int off = 1; off < 64; off <<= 1) v += __shfl_xor(v, off, 64);
  return v;
}

// ---------------------------------------------------------------------------
// bf16 MFMA GEMM: C[M64,Ncols] = A[M64,K] @ B[K,Ncols] (+bias). M64 % 64 == 0.
// Block = 4 waves in 2x2; each wave computes 32x32 via 2x2 MFMA 16x16x32 tiles.
template <int K, typename OutT>
__global__ __launch_bounds__(256) void mfma_gemm_kernel(
    const unsigned short* __restrict__ A, const unsigned short* __restrict__ Bp,
    const float* __restrict__ bias, OutT* __restrict__ C, int Ncols) {
  const int lane = threadIdx.x & 63;
  const int w = threadIdx.x >> 6;
  const int ml = lane & 15, kq = lane >> 4;
  const int row0 = blockIdx.y * 64 + (w >> 1) * 32;
  const int colt0 = blockIdx.x * 4 + (w & 1) * 2;
  constexpr int KB = K / 32;

  f32x4 acc00 = {}, acc01 = {}, acc10 = {}, acc11 = {};
  const unsigned short* a0 = A + (size_t)(row0 + ml) * K + kq * 8;
  const unsigned short* b0 = Bp + ((size_t)colt0 * KB * 64 + lane) * 8;
#pragma unroll
  for (int kb = 0; kb < KB; kb++) {
    bf16x8 af0 = __builtin_bit_cast(bf16x8, *(const uint4*)(a0 + kb * 32));
    bf16x8 af1 = __builtin_bit_cast(bf16x8, *(const uint4*)(a0 + 16 * K + kb * 32));
    bf16x8 bf0 = __builtin_bit_cast(bf16x8, *(const uint4*)(b0 + (size_t)kb * 512));
    bf16x8 bf1 = __builtin_bit_cast(bf16x8, *(const uint4*)(b0 + (size_t)(KB + kb) * 512));
    acc00 = __builtin_amdgcn_mfma_f32_16x16x32_bf16(af0, bf0, acc00, 0, 0, 0);
    acc01 = __builtin_amdgcn_mfma_f32_16x16x32_bf16(af0, bf1, acc01, 0, 0, 0);
    acc10 = __builtin_amdgcn_mfma_f32_16x16x32_bf16(af1, bf0, acc10, 0, 0, 0);
    acc11 = __builtin_amdgcn_mfma_f32_16x16x32_bf16(af1, bf1, acc11, 0, 0, 0);
  }
  const int c0 = colt0 * 16 + ml, c1 = c0 + 16;
  float bias0 = 0.f, bias1 = 0.f;
  if (bias) { bias0 = bias[c0]; bias1 = bias[c1]; }
#pragma unroll
  for (int r = 0; r < 4; r++) {
    const size_t rA = (size_t)(row0 + kq * 4 + r);
    const size_t rB = rA + 16;
    float v00 = acc00[r] + bias0, v01 = acc01[r] + bias1;
    float v10 = acc10[r] + bias0, v11 = acc11[r] + bias1;
    if constexpr (sizeof(OutT) == 2) {
      C[rA * Ncols + c0] = f2bf(v00);
      C[rA * Ncols + c1] = f2bf(v01);
      C[rB * Ncols + c0] = f2bf(v10);
      C[rB * Ncols + c1] = f2bf(v11);
    } else {
      C[rA * Ncols + c0] = v00;
      C[rA * Ncols + c1] = v01;
      C[rB * Ncols + c0] = v10;
      C[rB * Ncols + c1] = v11;
    }
  }
}

// Repack fp32 weight [K][Ncols] into bf16 B-fragment order.
__global__ void repack_b_kernel(const float* __restrict__ B, unsigned short* __restrict__ Bp,
                                int K, int Ncols) {
  const int idx = blockIdx.x * 256 + threadIdx.x;
  const int KB = K >> 5;
  const int total = (Ncols >> 4) * KB * 64;
  if (idx >= total) return;
  const int lane = idx & 63;
  const int kb = (idx >> 6) % KB;
  const int nt = idx / (KB << 6);
  const int ml = lane & 15, kq = lane >> 4;
  unsigned short* dst = Bp + (size_t)idx * 8;
#pragma unroll
  for (int j = 0; j < 8; j++)
    dst[j] = f2bf(B[(size_t)(kb * 32 + kq * 8 + j) * Ncols + nt * 16 + ml]);
}

__global__ void cast_bf16_kernel(const float* __restrict__ src,
                                 unsigned short* __restrict__ dst, int n4) {
  const int i = blockIdx.x * 256 + threadIdx.x;
  if (i >= n4) return;
  float4 v = ((const float4*)src)[i];
  ushort4 o;
  o.x = f2bf(v.x); o.y = f2bf(v.y); o.z = f2bf(v.z); o.w = f2bf(v.w);
  ((ushort4*)dst)[i] = o;
}

// ---------------------------------------------------------------------------
// Attention logits from bf16 features. One wave per node. VEC = H*C/64.
template <int H, int C, int VEC>
__global__ __launch_bounds__(256) void attn_kernel(
    const unsigned short* __restrict__ hfeat, const float* __restrict__ a_src,
    const float* __restrict__ a_dst, float* __restrict__ asrc,
    float* __restrict__ adst, int N) {
  const int DOUT = H * C;
  const int wave = threadIdx.x >> 6;
  const int lane = threadIdx.x & 63;
  const int n = blockIdx.x * 4 + wave;
  if (n >= N) return;

  const unsigned short* hr = &hfeat[(size_t)n * DOUT + lane * VEC];
  float hv[VEC], sv[VEC], dv[VEC];
  if constexpr (VEC == 4) {
    ushort4 t = *(const ushort4*)hr;
    hv[0] = bf2f(t.x); hv[1] = bf2f(t.y); hv[2] = bf2f(t.z); hv[3] = bf2f(t.w);
    float4 s = *(const float4*)&a_src[lane * 4];
    sv[0] = s.x; sv[1] = s.y; sv[2] = s.z; sv[3] = s.w;
    float4 d = *(const float4*)&a_dst[lane * 4];
    dv[0] = d.x; dv[1] = d.y; dv[2] = d.z; dv[3] = d.w;
  } else {
    ushort2 t = *(const ushort2*)hr;
    hv[0] = bf2f(t.x); hv[1] = bf2f(t.y);
    float2 s = *(const float2*)&a_src[lane * 2];
    sv[0] = s.x; sv[1] = s.y;
    float2 d = *(const float2*)&a_dst[lane * 2];
    dv[0] = d.x; dv[1] = d.y;
  }
  float ps = 0.f, pd = 0.f;
#pragma unroll
  for (int i = 0; i < VEC; i++) {
    ps += hv[i] * sv[i];
    pd += hv[i] * dv[i];
  }
  const int L = C / VEC;
#pragma unroll
  for (int off = 1; off < L; off <<= 1) {
    ps += __shfl_xor(ps, off, 64);
    pd += __shfl_xor(pd, off, 64);
  }
  if ((lane % L) == 0) {
    const int hh = lane / L;
    asrc[n * H + hh] = ps;
    adst[n * H + hh] = pd;
  }
}

// ---------------------------------------------------------------------------
// Single-pass GAT aggregate: out = (Σ p_j h_j)/(Σ p_j + eps), p = exp(lrelu(e)).
// Each lane walks all edges, so it accumulates its own denominator — no second
// pass, no per-edge divide, no dynamic register-array indexing in the loop.
// Then bias + LayerNorm + fp32 residual + ELU -> bf16.
template <int H, int C, int VEC>
__global__ __launch_bounds__(256) void gat_agg_kernel(
    const unsigned short* __restrict__ hfeat, const float* __restrict__ asrc,
    const float* __restrict__ adst, const int* __restrict__ rowptr,
    const int* __restrict__ col, const float* __restrict__ bias,
    const float* __restrict__ gamma, const float* __restrict__ beta,
    const float* __restrict__ proj, unsigned short* __restrict__ out, int N) {
  const int DOUT = H * C;
  const int wave = threadIdx.x >> 6;
  const int lane = threadIdx.x & 63;
  const int n = blockIdx.x * 4 + wave;
  if (n >= N) return;

  const int start = rowptr[n];
  const int deg = rowptr[n + 1] - start;
  const int myh = (lane * VEC) / C;       // loop-invariant head of this lane
  const float my_adl = adst[n * H + myh]; // hoisted (single dynamic access)

  using HT = typename std::conditional<VEC == 4, ushort4, ushort2>::type;

  float acc[VEC];
#pragma unroll
  for (int i = 0; i < VEC; i++) acc[i] = 0.f;
  float psum = 0.f;

  // one-deep software pipeline: col / asrc / h-row prefetched for j+1
  int src_n = (deg > 0) ? col[start] : n;
  float a_n = asrc[src_n * H + myh];
  HT h_n = *(const HT*)&hfeat[(size_t)src_n * DOUT + lane * VEC];

  for (int j = 0; j <= deg; j++) {
    const float a_c = a_n;
    const HT h_c = h_n;
    if (j < deg) {
      const int nsrc = (j + 1 < deg) ? col[start + j + 1] : n;
      a_n = asrc[nsrc * H + myh];
      h_n = *(const HT*)&hfeat[(size_t)nsrc * DOUT + lane * VEC];
    }
    float e = a_c + my_adl;
    e = (e > 0.f) ? e : 0.2f * e;
    const float p = __expf(e);
    psum += p;
    float hv[VEC];
    if constexpr (VEC == 4) {
      hv[0] = bf2f(h_c.x); hv[1] = bf2f(h_c.y); hv[2] = bf2f(h_c.z); hv[3] = bf2f(h_c.w);
    } else {
      hv[0] = bf2f(h_c.x); hv[1] = bf2f(h_c.y);
    }
#pragma unroll
    for (int i = 0; i < VEC; i++) acc[i] += hv[i] * p;
  }

  const float rs = 1.f / (psum + 1e-16f);

  // bias, LayerNorm over DOUT, + fp32 residual proj, ELU, bf16 store
  float m = 0.f;
#pragma unroll
  for (int i = 0; i < VEC; i++) {
    acc[i] = acc[i] * rs + bias[lane * VEC + i];
    m += acc[i];
  }
  m = wave_sum(m) / (float)DOUT;
  float vs = 0.f;
#pragma unroll
  for (int i = 0; i < VEC; i++) {
    const float d = acc[i] - m;
    vs += d * d;
  }
  vs = wave_sum(vs) / (float)DOUT;
  const float rstd = rsqrtf(vs + 1e-5f);

  const float* pr = &proj[(size_t)n * DOUT + lane * VEC];
  unsigned short* op = &out[(size_t)n * DOUT + lane * VEC];
#pragma unroll
  for (int i = 0; i < VEC; i++) {
    const int c = lane * VEC + i;
    float v = (acc[i] - m) * rstd * gamma[c] + beta[c] + pr[i];
    v = (v > 0.f) ? v : expm1f(v);
    op[i] = f2bf(v);
  }
}

// ---------------------------------------------------------------------------
// CSR build
__global__ void hist_kernel(const int* __restrict__ dst, int* __restrict__ cnt, int E) {
  const int e = blockIdx.x * 256 + threadIdx.x;
  if (e < E) atomicAdd(&cnt[dst[e]], 1);
}

// hierarchical exclusive scan over cnt -> rowptr (+cursor copy fused)
__global__ __launch_bounds__(256) void scan1_kernel(int* __restrict__ cnt,
                                                    int* __restrict__ sums, int N) {
  __shared__ int sm[256];
  const int i = blockIdx.x * 256 + threadIdx.x;
  const int v = (i < N) ? cnt[i] : 0;
  sm[threadIdx.x] = v;
  __syncthreads();
  for (int off = 1; off < 256; off <<= 1) {
    const int t = (threadIdx.x >= off) ? sm[threadIdx.x - off] : 0;
    __syncthreads();
    sm[threadIdx.x] += t;
    __syncthreads();
  }
  if (i < N) cnt[i] = sm[threadIdx.x] - v;  // exclusive within block (in-place)
  if (threadIdx.x == 255) sums[blockIdx.x] = sm[255];
}

__global__ __launch_bounds__(256) void scan2_kernel(int* __restrict__ sums, int nb) {
  __shared__ int sm[256];
  const int v = (threadIdx.x < nb) ? sums[threadIdx.x] : 0;
  sm[threadIdx.x] = v;
  __syncthreads();
  for (int off = 1; off < 256; off <<= 1) {
    const int t = (threadIdx.x >= off) ? sm[threadIdx.x - off] : 0;
    __syncthreads();
    sm[threadIdx.x] += t;
    __syncthreads();
  }
  if (threadIdx.x < nb) sums[threadIdx.x] = sm[threadIdx.x] - v;  // exclusive
}

__global__ void scan3_kernel(const int* __restrict__ cnt, const int* __restrict__ sums,
                             int* __restrict__ rowptr, int* __restrict__ cursor,
                             int N, int E) {
  const int i = blockIdx.x * 256 + threadIdx.x;
  if (i < N) {
    const int r = cnt[i] + sums[blockIdx.x];
    rowptr[i] = r;
    cursor[i] = r;
  }
  if (i == 0) rowptr[N] = E;
}

__global__ void scatter_kernel(const int* __restrict__ src, const int* __restrict__ dst,
                               int* __restrict__ cursor, int* __restrict__ col, int E) {
  const int e = blockIdx.x * 256 + threadIdx.x;
  if (e < E) {
    const int p = atomicAdd(&cursor[dst[e]], 1);
    col[p] = src[e];
  }
}

// ---------------------------------------------------------------------------
// Global mean pool per graph (batch sorted): one block per graph.
__global__ __launch_bounds__(128) void pool_kernel(const unsigned short* __restrict__ h3,
                                                   const int* __restrict__ batch,
                                                   float* __restrict__ out, int N) {
  __shared__ int sse[2];
  const int g = blockIdx.x;
  if (threadIdx.x == 0) {
    int lo = 0, hi = N;
    while (lo < hi) { const int mid = (lo + hi) >> 1; if (batch[mid] < g) lo = mid + 1; else hi = mid; }
    sse[0] = lo;
    lo = 0; hi = N;
    while (lo < hi) { const int mid = (lo + hi) >> 1; if (batch[mid] < g + 1) lo = mid + 1; else hi = mid; }
    sse[1] = lo;
  }
  __syncthreads();
  const int s = sse[0], e = sse[1];
  float sum = 0.f;
  for (int r = s; r < e; r++) sum += bf2f(h3[(size_t)r * 128 + threadIdx.x]);
  out[g * 128 + threadIdx.x] = (e > s) ? sum / (float)(e - s) : 0.f;
}

// ---------------------------------------------------------------------------
extern "C" void kernel_launch(void* const* d_in, const int* in_sizes, int n_in,
                              void* d_out, int out_size, void* d_ws, size_t ws_size,
                              hipStream_t stream) {
  const float* x      = (const float*)d_in[0];
  const int* edge_idx = (const int*)d_in[1];
  const int* batch    = (const int*)d_in[2];
  const float* W1     = (const float*)d_in[3];
  const float* a_src1 = (const float*)d_in[4];
  const float* a_dst1 = (const float*)d_in[5];
  const float* b1     = (const float*)d_in[6];
  const float* g1     = (const float*)d_in[7];
  const float* be1    = (const float*)d_in[8];
  const float* pw1    = (const float*)d_in[9];
  const float* pb1    = (const float*)d_in[10];
  const float* W2     = (const float*)d_in[11];
  const float* a_src2 = (const float*)d_in[12];
  const float* a_dst2 = (const float*)d_in[13];
  const float* b2     = (const float*)d_in[14];
  const float* g2     = (const float*)d_in[15];
  const float* be2    = (const float*)d_in[16];
  const float* pw2    = (const float*)d_in[17];
  const float* pb2    = (const float*)d_in[18];
  const float* W3     = (const float*)d_in[19];
  const float* a_src3 = (const float*)d_in[20];
  const float* a_dst3 = (const float*)d_in[21];
  const float* b3     = (const float*)d_in[22];
  const float* g3     = (const float*)d_in[23];
  const float* be3    = (const float*)d_in[24];
  const float* pw3    = (const float*)d_in[25];
  const float* pb3    = (const float*)d_in[26];

  const int NN = in_sizes[0] / 128;  // 50000
  const int E  = in_sizes[1] / 2;    // 800000
  const int G  = out_size / 128;     // 512
  const int M64 = (NN + 63) & ~63;   // 50048

  // workspace layout (256B-aligned)
  size_t off = 0;
  auto alloc = [&](size_t bytes) {
    size_t r = off;
    off += (bytes + 255) & ~(size_t)255;
    return r;
  };
  char* ws = (char*)d_ws;
  unsigned short* big0 = (unsigned short*)(ws + alloc((size_t)M64 * 256 * 2));  // h1feat / h3feat
  unsigned short* big1 = (unsigned short*)(ws + alloc((size_t)M64 * 256 * 2));  // h1out
  unsigned short* s0   = (unsigned short*)(ws + alloc((size_t)M64 * 128 * 2));  // xb / h2feat / h3out
  unsigned short* s1   = (unsigned short*)(ws + alloc((size_t)M64 * 128 * 2));  // h2out
  float* proj  = (float*)(ws + alloc((size_t)M64 * 256 * 4));                   // fp32 residual (reused)
  float* asrcB = (float*)(ws + alloc((size_t)NN * 8 * 4));
  float* adstB = (float*)(ws + alloc((size_t)NN * 8 * 4));
  int* rowptr  = (int*)(ws + alloc((size_t)(NN + 1) * 4));
  int* cnt     = (int*)(ws + alloc((size_t)NN * 4));
  int* cursor  = (int*)(ws + alloc((size_t)NN * 4));
  int* colb    = (int*)(ws + alloc((size_t)E * 4));
  int* sums    = (int*)(ws + alloc(256 * 4));
  unsigned short* BpW1 = (unsigned short*)(ws + alloc(128 * 256 * 2));
  unsigned short* BpP1 = (unsigned short*)(ws + alloc(128 * 256 * 2));
  unsigned short* BpW2 = (unsigned short*)(ws + alloc(256 * 128 * 2));
  unsigned short* BpP2 = (unsigned short*)(ws + alloc(256 * 128 * 2));
  unsigned short* BpW3 = (unsigned short*)(ws + alloc(128 * 128 * 2));
  unsigned short* BpP3 = (unsigned short*)(ws + alloc(128 * 128 * 2));
  (void)ws_size; (void)n_in;

  const int EB = (E + 255) / 256;
  const int NB = (NN + 255) / 256;  // 196
  const int NW = (NN + 3) / 4;
  const int MB = M64 / 64;
  const int pad = M64 - NN;

  // ---- CSR build (dst-sorted adjacency), reused by all 3 layers ----
  hipMemsetAsync(cnt, 0, (size_t)NN * 4, stream);
  hist_kernel<<<EB, 256, 0, stream>>>(edge_idx + E, cnt, E);
  scan1_kernel<<<NB, 256, 0, stream>>>(cnt, sums, NN);
  scan2_kernel<<<1, 256, 0, stream>>>(sums, NB);
  scan3_kernel<<<NB, 256, 0, stream>>>(cnt, sums, rowptr, cursor, NN, E);
  scatter_kernel<<<EB, 256, 0, stream>>>(edge_idx, edge_idx + E, cursor, colb, E);

  // ---- bf16 cast of x + pad-row zeroing for all GEMM A-inputs ----
  cast_bf16_kernel<<<(NN * 128 / 4 + 255) / 256, 256, 0, stream>>>(x, s0, NN * 128 / 4);
  if (pad) {
    hipMemsetAsync(s0 + (size_t)NN * 128, 0, (size_t)pad * 128 * 2, stream);   // xb pad
    hipMemsetAsync(big1 + (size_t)NN * 256, 0, (size_t)pad * 256 * 2, stream); // h1out pad
    hipMemsetAsync(s1 + (size_t)NN * 128, 0, (size_t)pad * 128 * 2, stream);   // h2out pad
  }

  // ---- weight repacks (tiny) ----
  repack_b_kernel<<<((256 / 16) * (128 / 32) * 64 + 255) / 256, 256, 0, stream>>>(W1, BpW1, 128, 256);
  repack_b_kernel<<<((256 / 16) * (128 / 32) * 64 + 255) / 256, 256, 0, stream>>>(pw1, BpP1, 128, 256);
  repack_b_kernel<<<((128 / 16) * (256 / 32) * 64 + 255) / 256, 256, 0, stream>>>(W2, BpW2, 256, 128);
  repack_b_kernel<<<((128 / 16) * (256 / 32) * 64 + 255) / 256, 256, 0, stream>>>(pw2, BpP2, 256, 128);
  repack_b_kernel<<<((128 / 16) * (128 / 32) * 64 + 255) / 256, 256, 0, stream>>>(W3, BpW3, 128, 128);
  repack_b_kernel<<<((128 / 16) * (128 / 32) * 64 + 255) / 256, 256, 0, stream>>>(pw3, BpP3, 128, 128);

  // ---- Layer 1: 128 -> 8x32 = 256 ----
  mfma_gemm_kernel<128, unsigned short><<<dim3(4, MB), 256, 0, stream>>>(s0, BpW1, nullptr, big0, 256);
  mfma_gemm_kernel<128, float><<<dim3(4, MB), 256, 0, stream>>>(s0, BpP1, pb1, proj, 256);
  attn_kernel<8, 32, 4><<<NW, 256, 0, stream>>>(big0, a_src1, a_dst1, asrcB, adstB, NN);
  gat_agg_kernel<8, 32, 4><<<NW, 256, 0, stream>>>(big0, asrcB, adstB, rowptr, colb, b1, g1, be1, proj, big1, NN);
  // big1 = h1 (bf16)

  // ---- Layer 2: 256 -> 4x32 = 128 ----
  mfma_gemm_kernel<256, unsigned short><<<dim3(2, MB), 256, 0, stream>>>(big1, BpW2, nullptr, s0, 128);
  mfma_gemm_kernel<256, float><<<dim3(2, MB), 256, 0, stream>>>(big1, BpP2, pb2, proj, 128);
  attn_kernel<4, 32, 2><<<NW, 256, 0, stream>>>(s0, a_src2, a_dst2, asrcB, adstB, NN);
  gat_agg_kernel<4, 32, 2><<<NW, 256, 0, stream>>>(s0, asrcB, adstB, rowptr, colb, b2, g2, be2, proj, s1, NN);
  // s1 = h2 (bf16)

  // ---- Layer 3: 128 -> 1x128, concat=False (1 head -> identity mean) ----
  mfma_gemm_kernel<128, unsigned short><<<dim3(2, MB), 256, 0, stream>>>(s1, BpW3, nullptr, big0, 128);
  mfma_gemm_kernel<128, float><<<dim3(2, MB), 256, 0, stream>>>(s1, BpP3, pb3, proj, 128);
  attn_kernel<1, 128, 2><<<NW, 256, 0, stream>>>(big0, a_src3, a_dst3, asrcB, adstB, NN);
  gat_agg_kernel<1, 128, 2><<<NW, 256, 0, stream>>>(big0, asrcB, adstB, rowptr, colb, b3, g3, be3, proj, s0, NN);
  // s0 = h3 (bf16)

  // ---- Global mean pool per graph ----
  pool_kernel<<<G, 128, 0, stream>>>(s0, batch, (float*)d_out, NN);
}

// Round 4
// 559.180 us; speedup vs baseline: 1.6960x; 1.2686x over previous
//
#include <hip/hip_runtime.h>
#include <math.h>

// N=50000, E=800000, G=512, IN=128, HID=32, H1=8, H2=4, OUT=128, D1=256, D2=128

typedef __bf16 bf16x8 __attribute__((ext_vector_type(8)));
typedef float f32x4 __attribute__((ext_vector_type(4)));

static __device__ __forceinline__ float bf2f(unsigned short u) {
  union { unsigned int i; float f; } c;
  c.i = ((unsigned int)u) << 16;
  return c.f;
}
static __device__ __forceinline__ unsigned short f2bf(float f) {
  __bf16 b = (__bf16)f;
  return __builtin_bit_cast(unsigned short, b);
}
static __device__ __forceinline__ float wave_sum(float v) {
#pragma unroll
  for (int off = 1; off < 64; off <<= 1) v += __shfl_xor(v, off, 64);
  return v;
}

// ---------------------------------------------------------------------------
// bf16 MFMA GEMM: C[M64,Ncols] = A[M64,K] @ B[K,Ncols] (+bias). M64 % 64 == 0.
template <int K, typename OutT>
__global__ __launch_bounds__(256) void mfma_gemm_kernel(
    const unsigned short* __restrict__ A, const unsigned short* __restrict__ Bp,
    const float* __restrict__ bias, OutT* __restrict__ C, int Ncols) {
  const int lane = threadIdx.x & 63;
  const int w = threadIdx.x >> 6;
  const int ml = lane & 15, kq = lane >> 4;
  const int row0 = blockIdx.y * 64 + (w >> 1) * 32;
  const int colt0 = blockIdx.x * 4 + (w & 1) * 2;
  constexpr int KB = K / 32;

  f32x4 acc00 = {}, acc01 = {}, acc10 = {}, acc11 = {};
  const unsigned short* a0 = A + (size_t)(row0 + ml) * K + kq * 8;
  const unsigned short* b0 = Bp + ((size_t)colt0 * KB * 64 + lane) * 8;
#pragma unroll
  for (int kb = 0; kb < KB; kb++) {
    bf16x8 af0 = __builtin_bit_cast(bf16x8, *(const uint4*)(a0 + kb * 32));
    bf16x8 af1 = __builtin_bit_cast(bf16x8, *(const uint4*)(a0 + 16 * K + kb * 32));
    bf16x8 bf0 = __builtin_bit_cast(bf16x8, *(const uint4*)(b0 + (size_t)kb * 512));
    bf16x8 bf1 = __builtin_bit_cast(bf16x8, *(const uint4*)(b0 + (size_t)(KB + kb) * 512));
    acc00 = __builtin_amdgcn_mfma_f32_16x16x32_bf16(af0, bf0, acc00, 0, 0, 0);
    acc01 = __builtin_amdgcn_mfma_f32_16x16x32_bf16(af0, bf1, acc01, 0, 0, 0);
    acc10 = __builtin_amdgcn_mfma_f32_16x16x32_bf16(af1, bf0, acc10, 0, 0, 0);
    acc11 = __builtin_amdgcn_mfma_f32_16x16x32_bf16(af1, bf1, acc11, 0, 0, 0);
  }
  const int c0 = colt0 * 16 + ml, c1 = c0 + 16;
  float bias0 = 0.f, bias1 = 0.f;
  if (bias) { bias0 = bias[c0]; bias1 = bias[c1]; }
#pragma unroll
  for (int r = 0; r < 4; r++) {
    const size_t rA = (size_t)(row0 + kq * 4 + r);
    const size_t rB = rA + 16;
    float v00 = acc00[r] + bias0, v01 = acc01[r] + bias1;
    float v10 = acc10[r] + bias0, v11 = acc11[r] + bias1;
    if constexpr (sizeof(OutT) == 2) {
      C[rA * Ncols + c0] = f2bf(v00);
      C[rA * Ncols + c1] = f2bf(v01);
      C[rB * Ncols + c0] = f2bf(v10);
      C[rB * Ncols + c1] = f2bf(v11);
    } else {
      C[rA * Ncols + c0] = v00;
      C[rA * Ncols + c1] = v01;
      C[rB * Ncols + c0] = v10;
      C[rB * Ncols + c1] = v11;
    }
  }
}

// Repack fp32 weight [K][Ncols] into bf16 B-fragment order.
__global__ void repack_b_kernel(const float* __restrict__ B, unsigned short* __restrict__ Bp,
                                int K, int Ncols) {
  const int idx = blockIdx.x * 256 + threadIdx.x;
  const int KB = K >> 5;
  const int total = (Ncols >> 4) * KB * 64;
  if (idx >= total) return;
  const int lane = idx & 63;
  const int kb = (idx >> 6) % KB;
  const int nt = idx / (KB << 6);
  const int ml = lane & 15, kq = lane >> 4;
  unsigned short* dst = Bp + (size_t)idx * 8;
#pragma unroll
  for (int j = 0; j < 8; j++)
    dst[j] = f2bf(B[(size_t)(kb * 32 + kq * 8 + j) * Ncols + nt * 16 + ml]);
}

__global__ void cast_bf16_kernel(const float* __restrict__ src,
                                 unsigned short* __restrict__ dst, int n4) {
  const int i = blockIdx.x * 256 + threadIdx.x;
  if (i >= n4) return;
  float4 v = ((const float4*)src)[i];
  ushort4 o;
  o.x = f2bf(v.x); o.y = f2bf(v.y); o.z = f2bf(v.z); o.w = f2bf(v.w);
  ((ushort4*)dst)[i] = o;
}

// ---------------------------------------------------------------------------
// Attention logits from bf16 features. One wave per node. VEC = H*C/64.
template <int H, int C, int VEC>
__global__ __launch_bounds__(256) void attn_kernel(
    const unsigned short* __restrict__ hfeat, const float* __restrict__ a_src,
    const float* __restrict__ a_dst, float* __restrict__ asrc,
    float* __restrict__ adst, int N) {
  const int DOUT = H * C;
  const int wave = threadIdx.x >> 6;
  const int lane = threadIdx.x & 63;
  const int n = blockIdx.x * 4 + wave;
  if (n >= N) return;

  const unsigned short* hr = &hfeat[(size_t)n * DOUT + lane * VEC];
  float hv[VEC], sv[VEC], dv[VEC];
  if constexpr (VEC == 4) {
    ushort4 t = *(const ushort4*)hr;
    hv[0] = bf2f(t.x); hv[1] = bf2f(t.y); hv[2] = bf2f(t.z); hv[3] = bf2f(t.w);
    float4 s = *(const float4*)&a_src[lane * 4];
    sv[0] = s.x; sv[1] = s.y; sv[2] = s.z; sv[3] = s.w;
    float4 d = *(const float4*)&a_dst[lane * 4];
    dv[0] = d.x; dv[1] = d.y; dv[2] = d.z; dv[3] = d.w;
  } else {
    ushort2 t = *(const ushort2*)hr;
    hv[0] = bf2f(t.x); hv[1] = bf2f(t.y);
    float2 s = *(const float2*)&a_src[lane * 2];
    sv[0] = s.x; sv[1] = s.y;
    float2 d = *(const float2*)&a_dst[lane * 2];
    dv[0] = d.x; dv[1] = d.y;
  }
  float ps = 0.f, pd = 0.f;
#pragma unroll
  for (int i = 0; i < VEC; i++) {
    ps += hv[i] * sv[i];
    pd += hv[i] * dv[i];
  }
  const int L = C / VEC;
#pragma unroll
  for (int off = 1; off < L; off <<= 1) {
    ps += __shfl_xor(ps, off, 64);
    pd += __shfl_xor(pd, off, 64);
  }
  if ((lane % L) == 0) {
    const int hh = lane / L;
    asrc[n * H + hh] = ps;
    adst[n * H + hh] = pd;
  }
}

// ---------------------------------------------------------------------------
// Single-pass GAT aggregate with high memory-level parallelism:
//  - wave-broadcast col chunk (one coalesced load per 64 edges, shfl thereafter)
//  - depth-4 double-buffered batched prefetch of (asrc, h-row) pairs
//  - SPLIT half-waves each own one edge (SPLIT=2 for DOUT=128 layers)
// Then bias + LayerNorm + bf16 residual + ELU -> bf16.
template <int H, int C, int SPLIT>
__global__ __launch_bounds__(256) void gat_agg_kernel(
    const unsigned short* __restrict__ hfeat, const float* __restrict__ asrc,
    const float* __restrict__ adst, const int* __restrict__ rowptr,
    const int* __restrict__ col, const float* __restrict__ bias,
    const float* __restrict__ gamma, const float* __restrict__ beta,
    const unsigned short* __restrict__ proj, unsigned short* __restrict__ out, int N) {
  constexpr int DOUT = H * C;
  constexpr int RL = DOUT / 4;  // lanes covering one row at ushort4/lane
  constexpr int PD = 4;         // prefetch batch (steps)
  const int wave = threadIdx.x >> 6;
  const int lane = threadIdx.x & 63;
  const int n = blockIdx.x * 4 + wave;
  if (n >= N) return;
  const int rl = lane % RL;
  const int sub = lane / RL;  // 0..SPLIT-1
  const int myh = (rl * 4) / C;
  const int start = rowptr[n];
  const int deg = rowptr[n + 1] - start;
  const int vlen = deg + 1;  // virtual edge deg = self-loop
  const float my_adl = adst[n * H + myh];

  float acc0 = 0.f, acc1 = 0.f, acc2 = 0.f, acc3 = 0.f, psum = 0.f;

  for (int chunk = 0; chunk < vlen; chunk += 64) {
    const int loc = chunk + lane;
    const int cv = (loc < deg) ? col[start + loc] : n;  // index deg -> self
    const int m = min(64, vlen - chunk);
    const int steps = (m + SPLIT - 1) / SPLIT;
    const int ngroups = (steps + PD - 1) / PD;

    float aA[PD], aB[PD];
    ushort4 hA[PD], hB[PD];

#pragma unroll
    for (int k = 0; k < PD; k++) {  // issue group 0 -> A
      const int local = k * SPLIT + sub;
      int s = __shfl(cv, local & 63);
      if (local >= m) s = n;
      aA[k] = asrc[s * H + myh];
      hA[k] = *(const ushort4*)&hfeat[(size_t)s * DOUT + rl * 4];
    }
    for (int g = 0; g < ngroups; g += 2) {
      if (g + 1 < ngroups) {
#pragma unroll
        for (int k = 0; k < PD; k++) {  // issue g+1 -> B
          const int local = ((g + 1) * PD + k) * SPLIT + sub;
          int s = __shfl(cv, local & 63);
          if (local >= m) s = n;
          aB[k] = asrc[s * H + myh];
          hB[k] = *(const ushort4*)&hfeat[(size_t)s * DOUT + rl * 4];
        }
      }
#pragma unroll
      for (int k = 0; k < PD; k++) {  // consume g (A)
        const int local = (g * PD + k) * SPLIT + sub;
        float e = aA[k] + my_adl;
        e = (e > 0.f) ? e : 0.2f * e;
        float p = __expf(e);
        p = (local < m) ? p : 0.f;
        psum += p;
        acc0 += bf2f(hA[k].x) * p;
        acc1 += bf2f(hA[k].y) * p;
        acc2 += bf2f(hA[k].z) * p;
        acc3 += bf2f(hA[k].w) * p;
      }
      if (g + 1 < ngroups) {
        if (g + 2 < ngroups) {
#pragma unroll
          for (int k = 0; k < PD; k++) {  // issue g+2 -> A
            const int local = ((g + 2) * PD + k) * SPLIT + sub;
            int s = __shfl(cv, local & 63);
            if (local >= m) s = n;
            aA[k] = asrc[s * H + myh];
            hA[k] = *(const ushort4*)&hfeat[(size_t)s * DOUT + rl * 4];
          }
        }
#pragma unroll
        for (int k = 0; k < PD; k++) {  // consume g+1 (B)
          const int local = ((g + 1) * PD + k) * SPLIT + sub;
          float e = aB[k] + my_adl;
          e = (e > 0.f) ? e : 0.2f * e;
          float p = __expf(e);
          p = (local < m) ? p : 0.f;
          psum += p;
          acc0 += bf2f(hB[k].x) * p;
          acc1 += bf2f(hB[k].y) * p;
          acc2 += bf2f(hB[k].z) * p;
          acc3 += bf2f(hB[k].w) * p;
        }
      }
    }
  }

  if constexpr (SPLIT == 2) {  // combine the two half-wave partials
    psum += __shfl_xor(psum, 32);
    acc0 += __shfl_xor(acc0, 32);
    acc1 += __shfl_xor(acc1, 32);
    acc2 += __shfl_xor(acc2, 32);
    acc3 += __shfl_xor(acc3, 32);
  }

  const float rs = 1.f / (psum + 1e-16f);
  const int c0 = rl * 4;
  const float4 bi = *(const float4*)&bias[c0];
  float v0 = acc0 * rs + bi.x;
  float v1 = acc1 * rs + bi.y;
  float v2 = acc2 * rs + bi.z;
  float v3 = acc3 * rs + bi.w;

  const float mean = wave_sum(v0 + v1 + v2 + v3) / (float)(DOUT * SPLIT);
  const float d0 = v0 - mean, d1 = v1 - mean, d2 = v2 - mean, d3 = v3 - mean;
  const float var = wave_sum(d0 * d0 + d1 * d1 + d2 * d2 + d3 * d3) / (float)(DOUT * SPLIT);
  const float rstd = rsqrtf(var + 1e-5f);

  const float4 ga = *(const float4*)&gamma[c0];
  const float4 be = *(const float4*)&beta[c0];
  const ushort4 pr = *(const ushort4*)&proj[(size_t)n * DOUT + c0];
  float o0 = d0 * rstd * ga.x + be.x + bf2f(pr.x);
  float o1 = d1 * rstd * ga.y + be.y + bf2f(pr.y);
  float o2 = d2 * rstd * ga.z + be.z + bf2f(pr.z);
  float o3 = d3 * rstd * ga.w + be.w + bf2f(pr.w);
  o0 = (o0 > 0.f) ? o0 : expm1f(o0);
  o1 = (o1 > 0.f) ? o1 : expm1f(o1);
  o2 = (o2 > 0.f) ? o2 : expm1f(o2);
  o3 = (o3 > 0.f) ? o3 : expm1f(o3);
  if (sub == 0) {
    ushort4 ov;
    ov.x = f2bf(o0); ov.y = f2bf(o1); ov.z = f2bf(o2); ov.w = f2bf(o3);
    *(ushort4*)&out[(size_t)n * DOUT + c0] = ov;
  }
}

// ---------------------------------------------------------------------------
// CSR build
__global__ void hist_kernel(const int* __restrict__ dst, int* __restrict__ cnt, int E) {
  const int e = blockIdx.x * 256 + threadIdx.x;
  if (e < E) atomicAdd(&cnt[dst[e]], 1);
}

__global__ __launch_bounds__(256) void scan1_kernel(int* __restrict__ cnt,
                                                    int* __restrict__ sums, int N) {
  __shared__ int sm[256];
  const int i = blockIdx.x * 256 + threadIdx.x;
  const int v = (i < N) ? cnt[i] : 0;
  sm[threadIdx.x] = v;
  __syncthreads();
  for (int off = 1; off < 256; off <<= 1) {
    const int t = (threadIdx.x >= off) ? sm[threadIdx.x - off] : 0;
    __syncthreads();
    sm[threadIdx.x] += t;
    __syncthreads();
  }
  if (i < N) cnt[i] = sm[threadIdx.x] - v;  // exclusive within block
  if (threadIdx.x == 255) sums[blockIdx.x] = sm[255];
}

__global__ __launch_bounds__(256) void scan2_kernel(int* __restrict__ sums, int nb) {
  __shared__ int sm[256];
  const int v = (threadIdx.x < nb) ? sums[threadIdx.x] : 0;
  sm[threadIdx.x] = v;
  __syncthreads();
  for (int off = 1; off < 256; off <<= 1) {
    const int t = (threadIdx.x >= off) ? sm[threadIdx.x - off] : 0;
    __syncthreads();
    sm[threadIdx.x] += t;
    __syncthreads();
  }
  if (threadIdx.x < nb) sums[threadIdx.x] = sm[threadIdx.x] - v;  // exclusive
}

__global__ void scan3_kernel(const int* __restrict__ cnt, const int* __restrict__ sums,
                             int* __restrict__ rowptr, int* __restrict__ cursor,
                             int N, int E) {
  const int i = blockIdx.x * 256 + threadIdx.x;
  if (i < N) {
    const int r = cnt[i] + sums[blockIdx.x];
    rowptr[i] = r;
    cursor[i] = r;
  }
  if (i == 0) rowptr[N] = E;
}

__global__ void scatter_kernel(const int* __restrict__ src, const int* __restrict__ dst,
                               int* __restrict__ cursor, int* __restrict__ col, int E) {
  const int e = blockIdx.x * 256 + threadIdx.x;
  if (e < E) {
    const int p = atomicAdd(&cursor[dst[e]], 1);
    col[p] = src[e];
  }
}

// ---------------------------------------------------------------------------
// Global mean pool per graph (batch sorted): one block per graph.
__global__ __launch_bounds__(128) void pool_kernel(const unsigned short* __restrict__ h3,
                                                   const int* __restrict__ batch,
                                                   float* __restrict__ out, int N) {
  __shared__ int sse[2];
  const int g = blockIdx.x;
  if (threadIdx.x == 0) {
    int lo = 0, hi = N;
    while (lo < hi) { const int mid = (lo + hi) >> 1; if (batch[mid] < g) lo = mid + 1; else hi = mid; }
    sse[0] = lo;
    lo = 0; hi = N;
    while (lo < hi) { const int mid = (lo + hi) >> 1; if (batch[mid] < g + 1) lo = mid + 1; else hi = mid; }
    sse[1] = lo;
  }
  __syncthreads();
  const int s = sse[0], e = sse[1];
  float sum = 0.f;
  for (int r = s; r < e; r++) sum += bf2f(h3[(size_t)r * 128 + threadIdx.x]);
  out[g * 128 + threadIdx.x] = (e > s) ? sum / (float)(e - s) : 0.f;
}

// ---------------------------------------------------------------------------
extern "C" void kernel_launch(void* const* d_in, const int* in_sizes, int n_in,
                              void* d_out, int out_size, void* d_ws, size_t ws_size,
                              hipStream_t stream) {
  const float* x      = (const float*)d_in[0];
  const int* edge_idx = (const int*)d_in[1];
  const int* batch    = (const int*)d_in[2];
  const float* W1     = (const float*)d_in[3];
  const float* a_src1 = (const float*)d_in[4];
  const float* a_dst1 = (const float*)d_in[5];
  const float* b1     = (const float*)d_in[6];
  const float* g1     = (const float*)d_in[7];
  const float* be1    = (const float*)d_in[8];
  const float* pw1    = (const float*)d_in[9];
  const float* pb1    = (const float*)d_in[10];
  const float* W2     = (const float*)d_in[11];
  const float* a_src2 = (const float*)d_in[12];
  const float* a_dst2 = (const float*)d_in[13];
  const float* b2     = (const float*)d_in[14];
  const float* g2     = (const float*)d_in[15];
  const float* be2    = (const float*)d_in[16];
  const float* pw2    = (const float*)d_in[17];
  const float* pb2    = (const float*)d_in[18];
  const float* W3     = (const float*)d_in[19];
  const float* a_src3 = (const float*)d_in[20];
  const float* a_dst3 = (const float*)d_in[21];
  const float* b3     = (const float*)d_in[22];
  const float* g3     = (const float*)d_in[23];
  const float* be3    = (const float*)d_in[24];
  const float* pw3    = (const float*)d_in[25];
  const float* pb3    = (const float*)d_in[26];

  const int NN = in_sizes[0] / 128;  // 50000
  const int E  = in_sizes[1] / 2;    // 800000
  const int G  = out_size / 128;     // 512
  const int M64 = (NN + 63) & ~63;   // 50048

  size_t off = 0;
  auto alloc = [&](size_t bytes) {
    size_t r = off;
    off += (bytes + 255) & ~(size_t)255;
    return r;
  };
  char* ws = (char*)d_ws;
  unsigned short* big0 = (unsigned short*)(ws + alloc((size_t)M64 * 256 * 2));  // h1feat / h3feat
  unsigned short* big1 = (unsigned short*)(ws + alloc((size_t)M64 * 256 * 2));  // h1out
  unsigned short* s0   = (unsigned short*)(ws + alloc((size_t)M64 * 128 * 2));  // xb / h2feat / h3out
  unsigned short* s1   = (unsigned short*)(ws + alloc((size_t)M64 * 128 * 2));  // h2out
  unsigned short* projb = (unsigned short*)(ws + alloc((size_t)M64 * 256 * 2)); // bf16 residual
  float* asrcB = (float*)(ws + alloc((size_t)NN * 8 * 4));
  float* adstB = (float*)(ws + alloc((size_t)NN * 8 * 4));
  int* rowptr  = (int*)(ws + alloc((size_t)(NN + 1) * 4));
  int* cnt     = (int*)(ws + alloc((size_t)NN * 4));
  int* cursor  = (int*)(ws + alloc((size_t)NN * 4));
  int* colb    = (int*)(ws + alloc((size_t)E * 4));
  int* sums    = (int*)(ws + alloc(256 * 4));
  unsigned short* BpW1 = (unsigned short*)(ws + alloc(128 * 256 * 2));
  unsigned short* BpP1 = (unsigned short*)(ws + alloc(128 * 256 * 2));
  unsigned short* BpW2 = (unsigned short*)(ws + alloc(256 * 128 * 2));
  unsigned short* BpP2 = (unsigned short*)(ws + alloc(256 * 128 * 2));
  unsigned short* BpW3 = (unsigned short*)(ws + alloc(128 * 128 * 2));
  unsigned short* BpP3 = (unsigned short*)(ws + alloc(128 * 128 * 2));
  (void)ws_size; (void)n_in;

  const int EB = (E + 255) / 256;
  const int NB = (NN + 255) / 256;  // 196
  const int NW = (NN + 3) / 4;
  const int MB = M64 / 64;
  const int pad = M64 - NN;

  // ---- CSR build (dst-sorted adjacency), reused by all 3 layers ----
  hipMemsetAsync(cnt, 0, (size_t)NN * 4, stream);
  hist_kernel<<<EB, 256, 0, stream>>>(edge_idx + E, cnt, E);
  scan1_kernel<<<NB, 256, 0, stream>>>(cnt, sums, NN);
  scan2_kernel<<<1, 256, 0, stream>>>(sums, NB);
  scan3_kernel<<<NB, 256, 0, stream>>>(cnt, sums, rowptr, cursor, NN, E);
  scatter_kernel<<<EB, 256, 0, stream>>>(edge_idx, edge_idx + E, cursor, colb, E);

  // ---- bf16 cast of x + pad-row zeroing for all GEMM A-inputs ----
  cast_bf16_kernel<<<(NN * 128 / 4 + 255) / 256, 256, 0, stream>>>(x, s0, NN * 128 / 4);
  if (pad) {
    hipMemsetAsync(s0 + (size_t)NN * 128, 0, (size_t)pad * 128 * 2, stream);   // xb pad
    hipMemsetAsync(big1 + (size_t)NN * 256, 0, (size_t)pad * 256 * 2, stream); // h1out pad
    hipMemsetAsync(s1 + (size_t)NN * 128, 0, (size_t)pad * 128 * 2, stream);   // h2out pad
  }

  // ---- weight repacks (tiny) ----
  repack_b_kernel<<<((256 / 16) * (128 / 32) * 64 + 255) / 256, 256, 0, stream>>>(W1, BpW1, 128, 256);
  repack_b_kernel<<<((256 / 16) * (128 / 32) * 64 + 255) / 256, 256, 0, stream>>>(pw1, BpP1, 128, 256);
  repack_b_kernel<<<((128 / 16) * (256 / 32) * 64 + 255) / 256, 256, 0, stream>>>(W2, BpW2, 256, 128);
  repack_b_kernel<<<((128 / 16) * (256 / 32) * 64 + 255) / 256, 256, 0, stream>>>(pw2, BpP2, 256, 128);
  repack_b_kernel<<<((128 / 16) * (128 / 32) * 64 + 255) / 256, 256, 0, stream>>>(W3, BpW3, 128, 128);
  repack_b_kernel<<<((128 / 16) * (128 / 32) * 64 + 255) / 256, 256, 0, stream>>>(pw3, BpP3, 128, 128);

  // ---- Layer 1: 128 -> 8x32 = 256 ----
  mfma_gemm_kernel<128, unsigned short><<<dim3(4, MB), 256, 0, stream>>>(s0, BpW1, nullptr, big0, 256);
  mfma_gemm_kernel<128, unsigned short><<<dim3(4, MB), 256, 0, stream>>>(s0, BpP1, pb1, projb, 256);
  attn_kernel<8, 32, 4><<<NW, 256, 0, stream>>>(big0, a_src1, a_dst1, asrcB, adstB, NN);
  gat_agg_kernel<8, 32, 1><<<NW, 256, 0, stream>>>(big0, asrcB, adstB, rowptr, colb, b1, g1, be1, projb, big1, NN);
  // big1 = h1 (bf16)

  // ---- Layer 2: 256 -> 4x32 = 128 ----
  mfma_gemm_kernel<256, unsigned short><<<dim3(2, MB), 256, 0, stream>>>(big1, BpW2, nullptr, s0, 128);
  mfma_gemm_kernel<256, unsigned short><<<dim3(2, MB), 256, 0, stream>>>(big1, BpP2, pb2, projb, 128);
  attn_kernel<4, 32, 2><<<NW, 256, 0, stream>>>(s0, a_src2, a_dst2, asrcB, adstB, NN);
  gat_agg_kernel<4, 32, 2><<<NW, 256, 0, stream>>>(s0, asrcB, adstB, rowptr, colb, b2, g2, be2, projb, s1, NN);
  // s1 = h2 (bf16)

  // ---- Layer 3: 128 -> 1x128, concat=False (1 head -> identity mean) ----
  mfma_gemm_kernel<128, unsigned short><<<dim3(2, MB), 256, 0, stream>>>(s1, BpW3, nullptr, big0, 128);
  mfma_gemm_kernel<128, unsigned short><<<dim3(2, MB), 256, 0, stream>>>(s1, BpP3, pb3, projb, 128);
  attn_kernel<1, 128, 2><<<NW, 256, 0, stream>>>(big0, a_src3, a_dst3, asrcB, adstB, NN);
  gat_agg_kernel<1, 128, 2><<<NW, 256, 0, stream>>>(big0, asrcB, adstB, rowptr, colb, b3, g3, be3, projb, s0, NN);
  // s0 = h3 (bf16)

  // ---- Global mean pool per graph ----
  pool_kernel<<<G, 128, 0, stream>>>(s0, batch, (float*)d_out, NN);
}

// Round 5
// 544.841 us; speedup vs baseline: 1.7407x; 1.0263x over previous
//
#include <hip/hip_runtime.h>
#include <math.h>

// N=50000, E=800000, G=512, IN=128, HID=32, H1=8, H2=4, OUT=128, D1=256, D2=128

typedef __bf16 bf16x8 __attribute__((ext_vector_type(8)));
typedef float f32x4 __attribute__((ext_vector_type(4)));

static __device__ __forceinline__ float bf2f(unsigned short u) {
  union { unsigned int i; float f; } c;
  c.i = ((unsigned int)u) << 16;
  return c.f;
}
static __device__ __forceinline__ unsigned short f2bf(float f) {
  __bf16 b = (__bf16)f;
  return __builtin_bit_cast(unsigned short, b);
}
static __device__ __forceinline__ float wave_sum(float v) {
#pragma unroll
  for (int off = 1; off < 64; off <<= 1) v += __shfl_xor(v, off, 64);
  return v;
}
// unpack 2 bf16 from a dword: low -> shift, high -> mask (1 VALU op each)
static __device__ __forceinline__ float bflo(unsigned int w) {
  union { unsigned int i; float f; } c;
  c.i = w << 16;
  return c.f;
}
static __device__ __forceinline__ float bfhi(unsigned int w) {
  union { unsigned int i; float f; } c;
  c.i = w & 0xFFFF0000u;
  return c.f;
}

// ---------------------------------------------------------------------------
// Fused dual bf16 MFMA GEMM: C1 = A@B1, C2 = A@B2 + bias2. Shared A fragments.
// Block = 4 waves in 2x2; each wave does a 32x32 tile of BOTH outputs.
template <int K>
__global__ __launch_bounds__(256) void fused_gemm_kernel(
    const unsigned short* __restrict__ A, const unsigned short* __restrict__ Bp1,
    const unsigned short* __restrict__ Bp2, const float* __restrict__ bias2,
    unsigned short* __restrict__ C1, unsigned short* __restrict__ C2, int Ncols) {
  const int lane = threadIdx.x & 63;
  const int w = threadIdx.x >> 6;
  const int ml = lane & 15, kq = lane >> 4;
  const int row0 = blockIdx.y * 64 + (w >> 1) * 32;
  const int colt0 = blockIdx.x * 4 + (w & 1) * 2;
  constexpr int KB = K / 32;

  f32x4 w00 = {}, w01 = {}, w10 = {}, w11 = {};
  f32x4 p00 = {}, p01 = {}, p10 = {}, p11 = {};
  const unsigned short* a0 = A + (size_t)(row0 + ml) * K + kq * 8;
  const unsigned short* b1 = Bp1 + ((size_t)colt0 * KB * 64 + lane) * 8;
  const unsigned short* b2 = Bp2 + ((size_t)colt0 * KB * 64 + lane) * 8;
#pragma unroll
  for (int kb = 0; kb < KB; kb++) {
    bf16x8 af0 = __builtin_bit_cast(bf16x8, *(const uint4*)(a0 + kb * 32));
    bf16x8 af1 = __builtin_bit_cast(bf16x8, *(const uint4*)(a0 + 16 * K + kb * 32));
    bf16x8 bw0 = __builtin_bit_cast(bf16x8, *(const uint4*)(b1 + (size_t)kb * 512));
    bf16x8 bw1 = __builtin_bit_cast(bf16x8, *(const uint4*)(b1 + (size_t)(KB + kb) * 512));
    bf16x8 bp0 = __builtin_bit_cast(bf16x8, *(const uint4*)(b2 + (size_t)kb * 512));
    bf16x8 bp1 = __builtin_bit_cast(bf16x8, *(const uint4*)(b2 + (size_t)(KB + kb) * 512));
    w00 = __builtin_amdgcn_mfma_f32_16x16x32_bf16(af0, bw0, w00, 0, 0, 0);
    w01 = __builtin_amdgcn_mfma_f32_16x16x32_bf16(af0, bw1, w01, 0, 0, 0);
    w10 = __builtin_amdgcn_mfma_f32_16x16x32_bf16(af1, bw0, w10, 0, 0, 0);
    w11 = __builtin_amdgcn_mfma_f32_16x16x32_bf16(af1, bw1, w11, 0, 0, 0);
    p00 = __builtin_amdgcn_mfma_f32_16x16x32_bf16(af0, bp0, p00, 0, 0, 0);
    p01 = __builtin_amdgcn_mfma_f32_16x16x32_bf16(af0, bp1, p01, 0, 0, 0);
    p10 = __builtin_amdgcn_mfma_f32_16x16x32_bf16(af1, bp0, p10, 0, 0, 0);
    p11 = __builtin_amdgcn_mfma_f32_16x16x32_bf16(af1, bp1, p11, 0, 0, 0);
  }
  const int c0 = colt0 * 16 + ml, c1 = c0 + 16;
  const float bi0 = bias2[c0], bi1 = bias2[c1];
#pragma unroll
  for (int r = 0; r < 4; r++) {
    const size_t rA = (size_t)(row0 + kq * 4 + r);
    const size_t rB = rA + 16;
    C1[rA * Ncols + c0] = f2bf(w00[r]);
    C1[rA * Ncols + c1] = f2bf(w01[r]);
    C1[rB * Ncols + c0] = f2bf(w10[r]);
    C1[rB * Ncols + c1] = f2bf(w11[r]);
    C2[rA * Ncols + c0] = f2bf(p00[r] + bi0);
    C2[rA * Ncols + c1] = f2bf(p01[r] + bi1);
    C2[rB * Ncols + c0] = f2bf(p10[r] + bi0);
    C2[rB * Ncols + c1] = f2bf(p11[r] + bi1);
  }
}

// Repack fp32 weight [K][Ncols] into bf16 B-fragment order.
__global__ void repack_b_kernel(const float* __restrict__ B, unsigned short* __restrict__ Bp,
                                int K, int Ncols) {
  const int idx = blockIdx.x * 256 + threadIdx.x;
  const int KB = K >> 5;
  const int total = (Ncols >> 4) * KB * 64;
  if (idx >= total) return;
  const int lane = idx & 63;
  const int kb = (idx >> 6) % KB;
  const int nt = idx / (KB << 6);
  const int ml = lane & 15, kq = lane >> 4;
  unsigned short* dst = Bp + (size_t)idx * 8;
#pragma unroll
  for (int j = 0; j < 8; j++)
    dst[j] = f2bf(B[(size_t)(kb * 32 + kq * 8 + j) * Ncols + nt * 16 + ml]);
}

__global__ void cast_bf16_kernel(const float* __restrict__ src,
                                 unsigned short* __restrict__ dst, int n4) {
  const int i = blockIdx.x * 256 + threadIdx.x;
  if (i >= n4) return;
  float4 v = ((const float4*)src)[i];
  ushort4 o;
  o.x = f2bf(v.x); o.y = f2bf(v.y); o.z = f2bf(v.z); o.w = f2bf(v.w);
  ((ushort4*)dst)[i] = o;
}

// ---------------------------------------------------------------------------
// Attention logits from bf16 features. One wave per node. VEC = H*C/64.
template <int H, int C, int VEC>
__global__ __launch_bounds__(256) void attn_kernel(
    const unsigned short* __restrict__ hfeat, const float* __restrict__ a_src,
    const float* __restrict__ a_dst, float* __restrict__ asrc,
    float* __restrict__ adst, int N) {
  const int DOUT = H * C;
  const int wave = threadIdx.x >> 6;
  const int lane = threadIdx.x & 63;
  const int n = blockIdx.x * 4 + wave;
  if (n >= N) return;

  const unsigned short* hr = &hfeat[(size_t)n * DOUT + lane * VEC];
  float hv[VEC], sv[VEC], dv[VEC];
  if constexpr (VEC == 4) {
    ushort4 t = *(const ushort4*)hr;
    hv[0] = bf2f(t.x); hv[1] = bf2f(t.y); hv[2] = bf2f(t.z); hv[3] = bf2f(t.w);
    float4 s = *(const float4*)&a_src[lane * 4];
    sv[0] = s.x; sv[1] = s.y; sv[2] = s.z; sv[3] = s.w;
    float4 d = *(const float4*)&a_dst[lane * 4];
    dv[0] = d.x; dv[1] = d.y; dv[2] = d.z; dv[3] = d.w;
  } else {
    ushort2 t = *(const ushort2*)hr;
    hv[0] = bf2f(t.x); hv[1] = bf2f(t.y);
    float2 s = *(const float2*)&a_src[lane * 2];
    sv[0] = s.x; sv[1] = s.y;
    float2 d = *(const float2*)&a_dst[lane * 2];
    dv[0] = d.x; dv[1] = d.y;
  }
  float ps = 0.f, pd = 0.f;
#pragma unroll
  for (int i = 0; i < VEC; i++) {
    ps += hv[i] * sv[i];
    pd += hv[i] * dv[i];
  }
  const int L = C / VEC;
#pragma unroll
  for (int off = 1; off < L; off <<= 1) {
    ps += __shfl_xor(ps, off, 64);
    pd += __shfl_xor(pd, off, 64);
  }
  if ((lane % L) == 0) {
    const int hh = lane / L;
    asrc[n * H + hh] = ps;
    adst[n * H + hh] = pd;
  }
}

// ---------------------------------------------------------------------------
// Single-pass GAT aggregate, 16B/lane gathers, SPLIT sub-waves each own an edge:
//  - wave-broadcast col chunk (one coalesced load per 64 edges, shfl thereafter)
//  - depth-4 double-buffered batched prefetch of (asrc, h-row16B) pairs
// Then bias + LayerNorm + bf16 residual + ELU -> bf16.
// RL = DOUT/8 lanes per row; SPLIT = 64/RL.
template <int H, int C, int SPLIT>
__global__ __launch_bounds__(256) void gat_agg_kernel(
    const unsigned short* __restrict__ hfeat, const float* __restrict__ asrc,
    const float* __restrict__ adst, const int* __restrict__ rowptr,
    const int* __restrict__ col, const float* __restrict__ bias,
    const float* __restrict__ gamma, const float* __restrict__ beta,
    const unsigned short* __restrict__ proj, unsigned short* __restrict__ out, int N) {
  constexpr int DOUT = H * C;
  constexpr int RL = DOUT / 8;  // lanes covering one row at ushort8/lane
  constexpr int PD = 4;         // prefetch batch (steps)
  const int wave = threadIdx.x >> 6;
  const int lane = threadIdx.x & 63;
  const int n = blockIdx.x * 4 + wave;
  if (n >= N) return;
  const int rl = lane % RL;
  const int sub = lane / RL;  // 0..SPLIT-1
  const int c0 = rl * 8;
  const int myh = c0 / C;
  const int start = rowptr[n];
  const int deg = rowptr[n + 1] - start;
  const int vlen = deg + 1;  // virtual edge deg = self-loop
  const float my_adl = adst[n * H + myh];

  float acc[8];
#pragma unroll
  for (int i = 0; i < 8; i++) acc[i] = 0.f;
  float psum = 0.f;

  for (int chunk = 0; chunk < vlen; chunk += 64) {
    const int loc = chunk + lane;
    const int cv = (loc < deg) ? col[start + loc] : n;  // index deg -> self
    const int m = min(64, vlen - chunk);
    const int steps = (m + SPLIT - 1) / SPLIT;
    const int ngroups = (steps + PD - 1) / PD;

    float aA[PD], aB[PD];
    uint4 hA[PD], hB[PD];

#pragma unroll
    for (int k = 0; k < PD; k++) {  // issue group 0 -> A
      const int local = k * SPLIT + sub;
      int s = __shfl(cv, local & 63);
      if (local >= m) s = n;
      aA[k] = asrc[s * H + myh];
      hA[k] = *(const uint4*)&hfeat[(size_t)s * DOUT + c0];
    }
    for (int g = 0; g < ngroups; g += 2) {
      if (g + 1 < ngroups) {
#pragma unroll
        for (int k = 0; k < PD; k++) {  // issue g+1 -> B
          const int local = ((g + 1) * PD + k) * SPLIT + sub;
          int s = __shfl(cv, local & 63);
          if (local >= m) s = n;
          aB[k] = asrc[s * H + myh];
          hB[k] = *(const uint4*)&hfeat[(size_t)s * DOUT + c0];
        }
      }
#pragma unroll
      for (int k = 0; k < PD; k++) {  // consume g (A)
        const int local = (g * PD + k) * SPLIT + sub;
        float e = aA[k] + my_adl;
        e = (e > 0.f) ? e : 0.2f * e;
        float p = __expf(e);
        p = (local < m) ? p : 0.f;
        psum += p;
        acc[0] += bflo(hA[k].x) * p; acc[1] += bfhi(hA[k].x) * p;
        acc[2] += bflo(hA[k].y) * p; acc[3] += bfhi(hA[k].y) * p;
        acc[4] += bflo(hA[k].z) * p; acc[5] += bfhi(hA[k].z) * p;
        acc[6] += bflo(hA[k].w) * p; acc[7] += bfhi(hA[k].w) * p;
      }
      if (g + 1 < ngroups) {
        if (g + 2 < ngroups) {
#pragma unroll
          for (int k = 0; k < PD; k++) {  // issue g+2 -> A
            const int local = ((g + 2) * PD + k) * SPLIT + sub;
            int s = __shfl(cv, local & 63);
            if (local >= m) s = n;
            aA[k] = asrc[s * H + myh];
            hA[k] = *(const uint4*)&hfeat[(size_t)s * DOUT + c0];
          }
        }
#pragma unroll
        for (int k = 0; k < PD; k++) {  // consume g+1 (B)
          const int local = ((g + 1) * PD + k) * SPLIT + sub;
          float e = aB[k] + my_adl;
          e = (e > 0.f) ? e : 0.2f * e;
          float p = __expf(e);
          p = (local < m) ? p : 0.f;
          psum += p;
          acc[0] += bflo(hB[k].x) * p; acc[1] += bfhi(hB[k].x) * p;
          acc[2] += bflo(hB[k].y) * p; acc[3] += bfhi(hB[k].y) * p;
          acc[4] += bflo(hB[k].z) * p; acc[5] += bfhi(hB[k].z) * p;
          acc[6] += bflo(hB[k].w) * p; acc[7] += bfhi(hB[k].w) * p;
        }
      }
    }
  }

  // combine SPLIT sub-wave partials (lanes with equal rl hold same channels)
#pragma unroll
  for (int o = RL; o < 64; o <<= 1) {
    psum += __shfl_xor(psum, o);
#pragma unroll
    for (int i = 0; i < 8; i++) acc[i] += __shfl_xor(acc[i], o);
  }

  const float rs = 1.f / (psum + 1e-16f);
  const float4 bi0 = *(const float4*)&bias[c0];
  const float4 bi1 = *(const float4*)&bias[c0 + 4];
  float v[8];
  v[0] = acc[0] * rs + bi0.x; v[1] = acc[1] * rs + bi0.y;
  v[2] = acc[2] * rs + bi0.z; v[3] = acc[3] * rs + bi0.w;
  v[4] = acc[4] * rs + bi1.x; v[5] = acc[5] * rs + bi1.y;
  v[6] = acc[6] * rs + bi1.z; v[7] = acc[7] * rs + bi1.w;

  float s8 = 0.f;
#pragma unroll
  for (int i = 0; i < 8; i++) s8 += v[i];
  const float mean = wave_sum(s8) / (float)(DOUT * SPLIT);
  float q8 = 0.f;
#pragma unroll
  for (int i = 0; i < 8; i++) {
    v[i] -= mean;
    q8 += v[i] * v[i];
  }
  const float var = wave_sum(q8) / (float)(DOUT * SPLIT);
  const float rstd = rsqrtf(var + 1e-5f);

  const float4 ga0 = *(const float4*)&gamma[c0];
  const float4 ga1 = *(const float4*)&gamma[c0 + 4];
  const float4 be0 = *(const float4*)&beta[c0];
  const float4 be1 = *(const float4*)&beta[c0 + 4];
  const uint4 pr = *(const uint4*)&proj[(size_t)n * DOUT + c0];
  float o0 = v[0] * rstd * ga0.x + be0.x + bflo(pr.x);
  float o1 = v[1] * rstd * ga0.y + be0.y + bfhi(pr.x);
  float o2 = v[2] * rstd * ga0.z + be0.z + bflo(pr.y);
  float o3 = v[3] * rstd * ga0.w + be0.w + bfhi(pr.y);
  float o4 = v[4] * rstd * ga1.x + be1.x + bflo(pr.z);
  float o5 = v[5] * rstd * ga1.y + be1.y + bfhi(pr.z);
  float o6 = v[6] * rstd * ga1.z + be1.z + bflo(pr.w);
  float o7 = v[7] * rstd * ga1.w + be1.w + bfhi(pr.w);
  o0 = (o0 > 0.f) ? o0 : expm1f(o0);
  o1 = (o1 > 0.f) ? o1 : expm1f(o1);
  o2 = (o2 > 0.f) ? o2 : expm1f(o2);
  o3 = (o3 > 0.f) ? o3 : expm1f(o3);
  o4 = (o4 > 0.f) ? o4 : expm1f(o4);
  o5 = (o5 > 0.f) ? o5 : expm1f(o5);
  o6 = (o6 > 0.f) ? o6 : expm1f(o6);
  o7 = (o7 > 0.f) ? o7 : expm1f(o7);
  if (sub == 0) {
    uint4 ov;
    ov.x = (unsigned int)f2bf(o0) | ((unsigned int)f2bf(o1) << 16);
    ov.y = (unsigned int)f2bf(o2) | ((unsigned int)f2bf(o3) << 16);
    ov.z = (unsigned int)f2bf(o4) | ((unsigned int)f2bf(o5) << 16);
    ov.w = (unsigned int)f2bf(o6) | ((unsigned int)f2bf(o7) << 16);
    *(uint4*)&out[(size_t)n * DOUT + c0] = ov;
  }
}

// ---------------------------------------------------------------------------
// CSR build
__global__ void hist_kernel(const int* __restrict__ dst, int* __restrict__ cnt, int E) {
  const int e = blockIdx.x * 256 + threadIdx.x;
  if (e < E) atomicAdd(&cnt[dst[e]], 1);
}

__global__ __launch_bounds__(256) void scan1_kernel(int* __restrict__ cnt,
                                                    int* __restrict__ sums, int N) {
  __shared__ int sm[256];
  const int i = blockIdx.x * 256 + threadIdx.x;
  const int v = (i < N) ? cnt[i] : 0;
  sm[threadIdx.x] = v;
  __syncthreads();
  for (int off = 1; off < 256; off <<= 1) {
    const int t = (threadIdx.x >= off) ? sm[threadIdx.x - off] : 0;
    __syncthreads();
    sm[threadIdx.x] += t;
    __syncthreads();
  }
  if (i < N) cnt[i] = sm[threadIdx.x] - v;  // exclusive within block
  if (threadIdx.x == 255) sums[blockIdx.x] = sm[255];
}

__global__ __launch_bounds__(256) void scan2_kernel(int* __restrict__ sums, int nb) {
  __shared__ int sm[256];
  const int v = (threadIdx.x < nb) ? sums[threadIdx.x] : 0;
  sm[threadIdx.x] = v;
  __syncthreads();
  for (int off = 1; off < 256; off <<= 1) {
    const int t = (threadIdx.x >= off) ? sm[threadIdx.x - off] : 0;
    __syncthreads();
    sm[threadIdx.x] += t;
    __syncthreads();
  }
  if (threadIdx.x < nb) sums[threadIdx.x] = sm[threadIdx.x] - v;  // exclusive
}

__global__ void scan3_kernel(const int* __restrict__ cnt, const int* __restrict__ sums,
                             int* __restrict__ rowptr, int* __restrict__ cursor,
                             int N, int E) {
  const int i = blockIdx.x * 256 + threadIdx.x;
  if (i < N) {
    const int r = cnt[i] + sums[blockIdx.x];
    rowptr[i] = r;
    cursor[i] = r;
  }
  if (i == 0) rowptr[N] = E;
}

__global__ void scatter_kernel(const int* __restrict__ src, const int* __restrict__ dst,
                               int* __restrict__ cursor, int* __restrict__ col, int E) {
  const int e = blockIdx.x * 256 + threadIdx.x;
  if (e < E) {
    const int p = atomicAdd(&cursor[dst[e]], 1);
    col[p] = src[e];
  }
}

// ---------------------------------------------------------------------------
// Global mean pool per graph (batch sorted): one block per graph.
__global__ __launch_bounds__(128) void pool_kernel(const unsigned short* __restrict__ h3,
                                                   const int* __restrict__ batch,
                                                   float* __restrict__ out, int N) {
  __shared__ int sse[2];
  const int g = blockIdx.x;
  if (threadIdx.x == 0) {
    int lo = 0, hi = N;
    while (lo < hi) { const int mid = (lo + hi) >> 1; if (batch[mid] < g) lo = mid + 1; else hi = mid; }
    sse[0] = lo;
    lo = 0; hi = N;
    while (lo < hi) { const int mid = (lo + hi) >> 1; if (batch[mid] < g + 1) lo = mid + 1; else hi = mid; }
    sse[1] = lo;
  }
  __syncthreads();
  const int s = sse[0], e = sse[1];
  float sum = 0.f;
  for (int r = s; r < e; r++) sum += bf2f(h3[(size_t)r * 128 + threadIdx.x]);
  out[g * 128 + threadIdx.x] = (e > s) ? sum / (float)(e - s) : 0.f;
}

// ---------------------------------------------------------------------------
extern "C" void kernel_launch(void* const* d_in, const int* in_sizes, int n_in,
                              void* d_out, int out_size, void* d_ws, size_t ws_size,
                              hipStream_t stream) {
  const float* x      = (const float*)d_in[0];
  const int* edge_idx = (const int*)d_in[1];
  const int* batch    = (const int*)d_in[2];
  const float* W1     = (const float*)d_in[3];
  const float* a_src1 = (const float*)d_in[4];
  const float* a_dst1 = (const float*)d_in[5];
  const float* b1     = (const float*)d_in[6];
  const float* g1     = (const float*)d_in[7];
  const float* be1    = (const float*)d_in[8];
  const float* pw1    = (const float*)d_in[9];
  const float* pb1    = (const float*)d_in[10];
  const float* W2     = (const float*)d_in[11];
  const float* a_src2 = (const float*)d_in[12];
  const float* a_dst2 = (const float*)d_in[13];
  const float* b2     = (const float*)d_in[14];
  const float* g2     = (const float*)d_in[15];
  const float* be2    = (const float*)d_in[16];
  const float* pw2    = (const float*)d_in[17];
  const float* pb2    = (const float*)d_in[18];
  const float* W3     = (const float*)d_in[19];
  const float* a_src3 = (const float*)d_in[20];
  const float* a_dst3 = (const float*)d_in[21];
  const float* b3     = (const float*)d_in[22];
  const float* g3     = (const float*)d_in[23];
  const float* be3    = (const float*)d_in[24];
  const float* pw3    = (const float*)d_in[25];
  const float* pb3    = (const float*)d_in[26];

  const int NN = in_sizes[0] / 128;  // 50000
  const int E  = in_sizes[1] / 2;    // 800000
  const int G  = out_size / 128;     // 512
  const int M64 = (NN + 63) & ~63;   // 50048

  size_t off = 0;
  auto alloc = [&](size_t bytes) {
    size_t r = off;
    off += (bytes + 255) & ~(size_t)255;
    return r;
  };
  char* ws = (char*)d_ws;
  unsigned short* big0 = (unsigned short*)(ws + alloc((size_t)M64 * 256 * 2));  // h1feat / h3feat
  unsigned short* big1 = (unsigned short*)(ws + alloc((size_t)M64 * 256 * 2));  // h1out
  unsigned short* s0   = (unsigned short*)(ws + alloc((size_t)M64 * 128 * 2));  // xb / h2feat / h3out
  unsigned short* s1   = (unsigned short*)(ws + alloc((size_t)M64 * 128 * 2));  // h2out
  unsigned short* projb = (unsigned short*)(ws + alloc((size_t)M64 * 256 * 2)); // bf16 residual
  float* asrcB = (float*)(ws + alloc((size_t)NN * 8 * 4));
  float* adstB = (float*)(ws + alloc((size_t)NN * 8 * 4));
  int* rowptr  = (int*)(ws + alloc((size_t)(NN + 1) * 4));
  int* cnt     = (int*)(ws + alloc((size_t)NN * 4));
  int* cursor  = (int*)(ws + alloc((size_t)NN * 4));
  int* colb    = (int*)(ws + alloc((size_t)E * 4));
  int* sums    = (int*)(ws + alloc(256 * 4));
  unsigned short* BpW1 = (unsigned short*)(ws + alloc(128 * 256 * 2));
  unsigned short* BpP1 = (unsigned short*)(ws + alloc(128 * 256 * 2));
  unsigned short* BpW2 = (unsigned short*)(ws + alloc(256 * 128 * 2));
  unsigned short* BpP2 = (unsigned short*)(ws + alloc(256 * 128 * 2));
  unsigned short* BpW3 = (unsigned short*)(ws + alloc(128 * 128 * 2));
  unsigned short* BpP3 = (unsigned short*)(ws + alloc(128 * 128 * 2));
  (void)ws_size; (void)n_in;

  const int EB = (E + 255) / 256;
  const int NB = (NN + 255) / 256;  // 196
  const int NW = (NN + 3) / 4;
  const int MB = M64 / 64;
  const int pad = M64 - NN;

  // ---- CSR build (dst-sorted adjacency), reused by all 3 layers ----
  hipMemsetAsync(cnt, 0, (size_t)NN * 4, stream);
  hist_kernel<<<EB, 256, 0, stream>>>(edge_idx + E, cnt, E);
  scan1_kernel<<<NB, 256, 0, stream>>>(cnt, sums, NN);
  scan2_kernel<<<1, 256, 0, stream>>>(sums, NB);
  scan3_kernel<<<NB, 256, 0, stream>>>(cnt, sums, rowptr, cursor, NN, E);
  scatter_kernel<<<EB, 256, 0, stream>>>(edge_idx, edge_idx + E, cursor, colb, E);

  // ---- bf16 cast of x + pad-row zeroing for all GEMM A-inputs ----
  cast_bf16_kernel<<<(NN * 128 / 4 + 255) / 256, 256, 0, stream>>>(x, s0, NN * 128 / 4);
  if (pad) {
    hipMemsetAsync(s0 + (size_t)NN * 128, 0, (size_t)pad * 128 * 2, stream);   // xb pad
    hipMemsetAsync(big1 + (size_t)NN * 256, 0, (size_t)pad * 256 * 2, stream); // h1out pad
    hipMemsetAsync(s1 + (size_t)NN * 128, 0, (size_t)pad * 128 * 2, stream);   // h2out pad
  }

  // ---- weight repacks (tiny) ----
  repack_b_kernel<<<((256 / 16) * (128 / 32) * 64 + 255) / 256, 256, 0, stream>>>(W1, BpW1, 128, 256);
  repack_b_kernel<<<((256 / 16) * (128 / 32) * 64 + 255) / 256, 256, 0, stream>>>(pw1, BpP1, 128, 256);
  repack_b_kernel<<<((128 / 16) * (256 / 32) * 64 + 255) / 256, 256, 0, stream>>>(W2, BpW2, 256, 128);
  repack_b_kernel<<<((128 / 16) * (256 / 32) * 64 + 255) / 256, 256, 0, stream>>>(pw2, BpP2, 256, 128);
  repack_b_kernel<<<((128 / 16) * (128 / 32) * 64 + 255) / 256, 256, 0, stream>>>(W3, BpW3, 128, 128);
  repack_b_kernel<<<((128 / 16) * (128 / 32) * 64 + 255) / 256, 256, 0, stream>>>(pw3, BpP3, 128, 128);

  // ---- Layer 1: 128 -> 8x32 = 256 ----
  fused_gemm_kernel<128><<<dim3(4, MB), 256, 0, stream>>>(s0, BpW1, BpP1, pb1, big0, projb, 256);
  attn_kernel<8, 32, 4><<<NW, 256, 0, stream>>>(big0, a_src1, a_dst1, asrcB, adstB, NN);
  gat_agg_kernel<8, 32, 2><<<NW, 256, 0, stream>>>(big0, asrcB, adstB, rowptr, colb, b1, g1, be1, projb, big1, NN);
  // big1 = h1 (bf16)

  // ---- Layer 2: 256 -> 4x32 = 128 ----
  fused_gemm_kernel<256><<<dim3(2, MB), 256, 0, stream>>>(big1, BpW2, BpP2, pb2, s0, projb, 128);
  attn_kernel<4, 32, 2><<<NW, 256, 0, stream>>>(s0, a_src2, a_dst2, asrcB, adstB, NN);
  gat_agg_kernel<4, 32, 4><<<NW, 256, 0, stream>>>(s0, asrcB, adstB, rowptr, colb, b2, g2, be2, projb, s1, NN);
  // s1 = h2 (bf16)

  // ---- Layer 3: 128 -> 1x128, concat=False (1 head -> identity mean) ----
  fused_gemm_kernel<128><<<dim3(2, MB), 256, 0, stream>>>(s1, BpW3, BpP3, pb3, big0, projb, 128);
  attn_kernel<1, 128, 2><<<NW, 256, 0, stream>>>(big0, a_src3, a_dst3, asrcB, adstB, NN);
  gat_agg_kernel<1, 128, 4><<<NW, 256, 0, stream>>>(big0, asrcB, adstB, rowptr, colb, b3, g3, be3, projb, s0, NN);
  // s0 = h3 (bf16)

  // ---- Global mean pool per graph ----
  pool_kernel<<<G, 128, 0, stream>>>(s0, batch, (float*)d_out, NN);
}

// Round 6
// 498.144 us; speedup vs baseline: 1.9038x; 1.0937x over previous
//
#include <hip/hip_runtime.h>
#include <hip/hip_fp16.h>
#include <math.h>

// N=50000, E=800000, G=512, IN=128, HID=32, H1=8, H2=4, OUT=128, D1=256, D2=128

typedef _Float16 f16x8 __attribute__((ext_vector_type(8)));
typedef float f32x4 __attribute__((ext_vector_type(4)));

static __device__ __forceinline__ float h2f(unsigned short u) {
  return __half2float(__builtin_bit_cast(__half, u));
}
static __device__ __forceinline__ unsigned short f2h(float f) {
  return __builtin_bit_cast(unsigned short, __float2half_rn(f));
}
static __device__ __forceinline__ float hlo(unsigned int w) {
  return __low2float(__builtin_bit_cast(__half2, w));
}
static __device__ __forceinline__ float hhi(unsigned int w) {
  return __high2float(__builtin_bit_cast(__half2, w));
}
static __device__ __forceinline__ float wave_sum(float v) {
#pragma unroll
  for (int off = 1; off < 64; off <<= 1) v += __shfl_xor(v, off, 64);
  return v;
}

// ---------------------------------------------------------------------------
// Fused dual f16 MFMA GEMM + attention-logit epilogue.
// C1 = A@B1 (= h, no bias), C2 = A@B2 + bias2 (= proj). Shared A fragments.
// Epilogue: asrc[row,h] += sum_c h[row,c]*a_src[h,c%C] for this wave's 32 cols
// (exactly one head when C==32 -> plain store; C==128 spans 4 waves -> atomic).
template <int K, int C, int H, bool ATOMIC>
__global__ __launch_bounds__(256) void fused_gemm_kernel(
    const unsigned short* __restrict__ A, const unsigned short* __restrict__ Bp1,
    const unsigned short* __restrict__ Bp2, const float* __restrict__ bias2,
    const float* __restrict__ a_src, const float* __restrict__ a_dst,
    unsigned short* __restrict__ C1, unsigned short* __restrict__ C2,
    float* __restrict__ asrc, float* __restrict__ adst, int Ncols) {
  const int lane = threadIdx.x & 63;
  const int w = threadIdx.x >> 6;
  const int ml = lane & 15, kq = lane >> 4;
  const int row0 = blockIdx.y * 64 + (w >> 1) * 32;
  const int colt0 = blockIdx.x * 4 + (w & 1) * 2;
  constexpr int KB = K / 32;

  f32x4 w00 = {}, w01 = {}, w10 = {}, w11 = {};
  f32x4 p00 = {}, p01 = {}, p10 = {}, p11 = {};
  const unsigned short* a0 = A + (size_t)(row0 + ml) * K + kq * 8;
  const unsigned short* b1 = Bp1 + ((size_t)colt0 * KB * 64 + lane) * 8;
  const unsigned short* b2 = Bp2 + ((size_t)colt0 * KB * 64 + lane) * 8;
#pragma unroll
  for (int kb = 0; kb < KB; kb++) {
    f16x8 af0 = __builtin_bit_cast(f16x8, *(const uint4*)(a0 + kb * 32));
    f16x8 af1 = __builtin_bit_cast(f16x8, *(const uint4*)(a0 + 16 * K + kb * 32));
    f16x8 bw0 = __builtin_bit_cast(f16x8, *(const uint4*)(b1 + (size_t)kb * 512));
    f16x8 bw1 = __builtin_bit_cast(f16x8, *(const uint4*)(b1 + (size_t)(KB + kb) * 512));
    f16x8 bp0 = __builtin_bit_cast(f16x8, *(const uint4*)(b2 + (size_t)kb * 512));
    f16x8 bp1 = __builtin_bit_cast(f16x8, *(const uint4*)(b2 + (size_t)(KB + kb) * 512));
    w00 = __builtin_amdgcn_mfma_f32_16x16x32_f16(af0, bw0, w00, 0, 0, 0);
    w01 = __builtin_amdgcn_mfma_f32_16x16x32_f16(af0, bw1, w01, 0, 0, 0);
    w10 = __builtin_amdgcn_mfma_f32_16x16x32_f16(af1, bw0, w10, 0, 0, 0);
    w11 = __builtin_amdgcn_mfma_f32_16x16x32_f16(af1, bw1, w11, 0, 0, 0);
    p00 = __builtin_amdgcn_mfma_f32_16x16x32_f16(af0, bp0, p00, 0, 0, 0);
    p01 = __builtin_amdgcn_mfma_f32_16x16x32_f16(af0, bp1, p01, 0, 0, 0);
    p10 = __builtin_amdgcn_mfma_f32_16x16x32_f16(af1, bp0, p10, 0, 0, 0);
    p11 = __builtin_amdgcn_mfma_f32_16x16x32_f16(af1, bp1, p11, 0, 0, 0);
  }
  const int c0 = colt0 * 16 + ml, c1 = c0 + 16;
  const float bi0 = bias2[c0], bi1 = bias2[c1];
#pragma unroll
  for (int r = 0; r < 4; r++) {
    const size_t rA = (size_t)(row0 + kq * 4 + r);
    const size_t rB = rA + 16;
    C1[rA * Ncols + c0] = f2h(w00[r]);
    C1[rA * Ncols + c1] = f2h(w01[r]);
    C1[rB * Ncols + c0] = f2h(w10[r]);
    C1[rB * Ncols + c1] = f2h(w11[r]);
    C2[rA * Ncols + c0] = f2h(p00[r] + bi0);
    C2[rA * Ncols + c1] = f2h(p01[r] + bi1);
    C2[rB * Ncols + c0] = f2h(p10[r] + bi0);
    C2[rB * Ncols + c1] = f2h(p11[r] + bi1);
  }

  // ---- attention-logit epilogue (pre-bias W-accs == h) ----
  const int hh = (colt0 * 16) / C;
  const float aS0 = a_src[hh * C + (c0 % C)], aS1 = a_src[hh * C + (c1 % C)];
  const float aD0 = a_dst[hh * C + (c0 % C)], aD1 = a_dst[hh * C + (c1 % C)];
  float pS0[4], pD0[4], pS1[4], pD1[4];
#pragma unroll
  for (int r = 0; r < 4; r++) {
    pS0[r] = w00[r] * aS0 + w01[r] * aS1;
    pD0[r] = w00[r] * aD0 + w01[r] * aD1;
    pS1[r] = w10[r] * aS0 + w11[r] * aS1;
    pD1[r] = w10[r] * aD0 + w11[r] * aD1;
  }
#pragma unroll
  for (int off = 1; off < 16; off <<= 1) {
#pragma unroll
    for (int r = 0; r < 4; r++) {
      pS0[r] += __shfl_xor(pS0[r], off);
      pD0[r] += __shfl_xor(pD0[r], off);
      pS1[r] += __shfl_xor(pS1[r], off);
      pD1[r] += __shfl_xor(pD1[r], off);
    }
  }
  if (ml < 4) {
    const int r = ml;
    const int rowA = row0 + kq * 4 + r;
    const int rowB = rowA + 16;
    if constexpr (ATOMIC) {
      atomicAdd(&asrc[rowA * H + hh], pS0[r]);
      atomicAdd(&adst[rowA * H + hh], pD0[r]);
      atomicAdd(&asrc[rowB * H + hh], pS1[r]);
      atomicAdd(&adst[rowB * H + hh], pD1[r]);
    } else {
      asrc[rowA * H + hh] = pS0[r];
      adst[rowA * H + hh] = pD0[r];
      asrc[rowB * H + hh] = pS1[r];
      adst[rowB * H + hh] = pD1[r];
    }
  }
}

// ---------------------------------------------------------------------------
// One kernel repacking all 6 fp32 weights into f16 B-fragment order.
static __device__ __forceinline__ void repack_one(const float* B, unsigned short* Bp,
                                                  int K, int Ncols, int idx) {
  const int KB = K >> 5;
  const int lane = idx & 63;
  const int kb = (idx >> 6) % KB;
  const int nt = idx / (KB << 6);
  const int ml = lane & 15, kq = lane >> 4;
  unsigned short* dst = Bp + (size_t)idx * 8;
#pragma unroll
  for (int j = 0; j < 8; j++)
    dst[j] = f2h(B[(size_t)(kb * 32 + kq * 8 + j) * Ncols + nt * 16 + ml]);
}

__global__ __launch_bounds__(256) void repack_all_kernel(
    const float* W1, const float* pw1, const float* W2, const float* pw2,
    const float* W3, const float* pw3, unsigned short* BpW1, unsigned short* BpP1,
    unsigned short* BpW2, unsigned short* BpP2, unsigned short* BpW3,
    unsigned short* BpP3) {
  int idx = blockIdx.x * 256 + threadIdx.x;  // 20480 total
  if (idx < 4096) { repack_one(W1, BpW1, 128, 256, idx); return; }
  idx -= 4096;
  if (idx < 4096) { repack_one(pw1, BpP1, 128, 256, idx); return; }
  idx -= 4096;
  if (idx < 4096) { repack_one(W2, BpW2, 256, 128, idx); return; }
  idx -= 4096;
  if (idx < 4096) { repack_one(pw2, BpP2, 256, 128, idx); return; }
  idx -= 4096;
  if (idx < 2048) { repack_one(W3, BpW3, 128, 128, idx); return; }
  idx -= 2048;
  repack_one(pw3, BpP3, 128, 128, idx);
}

// cast x -> f16, zeroing pad rows (grid covers M64 rows)
__global__ void cast_f16_kernel(const float* __restrict__ src,
                                unsigned short* __restrict__ dst, int n4, int pad4) {
  const int i = blockIdx.x * 256 + threadIdx.x;
  if (i >= n4 + pad4) return;
  ushort4 o;
  if (i < n4) {
    float4 v = ((const float4*)src)[i];
    o.x = f2h(v.x); o.y = f2h(v.y); o.z = f2h(v.z); o.w = f2h(v.w);
  } else {
    o.x = o.y = o.z = o.w = 0;
  }
  ((ushort4*)dst)[i] = o;
}

// zero the pad rows of the two agg-output buffers (h1out 256-wide, h2out 128-wide)
__global__ void zero_pads_kernel(unsigned short* b256, unsigned short* b128, int pad) {
  const int i = blockIdx.x * 256 + threadIdx.x;
  if (i < pad * 256) b256[i] = 0;
  if (i < pad * 128) b128[i] = 0;
}

__global__ void zero2_kernel(float* a, float* b, int n) {
  const int i = blockIdx.x * 256 + threadIdx.x;
  if (i < n) { a[i] = 0.f; b[i] = 0.f; }
}

// ---------------------------------------------------------------------------
// Single-pass GAT aggregate, 16B/lane gathers, packed-f16 MAC inner loop:
//  - wave-broadcast col chunk; depth-4 double-buffered (asrc, h-row) prefetch
//  - v_pk_fma_f16 accumulation (4 instr / 8 ch), fp32 flush per <=64-edge chunk
// Then bias + LayerNorm + f16 residual + ELU -> f16.
template <int H, int C, int SPLIT>
__global__ __launch_bounds__(256) void gat_agg_kernel(
    const unsigned short* __restrict__ hfeat, const float* __restrict__ asrc,
    const float* __restrict__ adst, const int* __restrict__ rowptr,
    const int* __restrict__ col, const float* __restrict__ bias,
    const float* __restrict__ gamma, const float* __restrict__ beta,
    const unsigned short* __restrict__ proj, unsigned short* __restrict__ out, int N) {
  constexpr int DOUT = H * C;
  constexpr int RL = DOUT / 8;  // lanes covering one row at 8 halfs/lane
  constexpr int PD = 4;         // prefetch batch (steps)
  const int wave = threadIdx.x >> 6;
  const int lane = threadIdx.x & 63;
  const int n = blockIdx.x * 4 + wave;
  if (n >= N) return;
  const int rl = lane % RL;
  const int sub = lane / RL;  // 0..SPLIT-1
  const int c0 = rl * 8;
  const int myh = c0 / C;
  const int start = rowptr[n];
  const int deg = rowptr[n + 1] - start;
  const int vlen = deg + 1;  // virtual edge deg = self-loop
  const float my_adl = adst[n * H + myh];

  float acc[8];
#pragma unroll
  for (int i = 0; i < 8; i++) acc[i] = 0.f;
  float psum = 0.f;
  const __half2 hz = __float2half2_rn(0.f);

  for (int chunk = 0; chunk < vlen; chunk += 64) {
    const int loc = chunk + lane;
    const int cv = (loc < deg) ? col[start + loc] : n;  // index deg -> self
    const int m = min(64, vlen - chunk);
    const int steps = (m + SPLIT - 1) / SPLIT;
    const int ngroups = (steps + PD - 1) / PD;

    __half2 acc2[4] = {hz, hz, hz, hz};
    float aA[PD], aB[PD];
    uint4 hA[PD], hB[PD];

#pragma unroll
    for (int k = 0; k < PD; k++) {  // issue group 0 -> A
      const int local = k * SPLIT + sub;
      int s = __shfl(cv, local & 63);
      if (local >= m) s = n;
      aA[k] = asrc[s * H + myh];
      hA[k] = *(const uint4*)&hfeat[(size_t)s * DOUT + c0];
    }
    for (int g = 0; g < ngroups; g += 2) {
      if (g + 1 < ngroups) {
#pragma unroll
        for (int k = 0; k < PD; k++) {  // issue g+1 -> B
          const int local = ((g + 1) * PD + k) * SPLIT + sub;
          int s = __shfl(cv, local & 63);
          if (local >= m) s = n;
          aB[k] = asrc[s * H + myh];
          hB[k] = *(const uint4*)&hfeat[(size_t)s * DOUT + c0];
        }
      }
#pragma unroll
      for (int k = 0; k < PD; k++) {  // consume g (A)
        const int local = (g * PD + k) * SPLIT + sub;
        float e = aA[k] + my_adl;
        e = (e > 0.f) ? e : 0.2f * e;
        float p = __expf(e);
        p = (local < m) ? p : 0.f;
        psum += p;
        const __half2 pp = __float2half2_rn(p);
        acc2[0] = __hfma2(__builtin_bit_cast(__half2, hA[k].x), pp, acc2[0]);
        acc2[1] = __hfma2(__builtin_bit_cast(__half2, hA[k].y), pp, acc2[1]);
        acc2[2] = __hfma2(__builtin_bit_cast(__half2, hA[k].z), pp, acc2[2]);
        acc2[3] = __hfma2(__builtin_bit_cast(__half2, hA[k].w), pp, acc2[3]);
      }
      if (g + 1 < ngroups) {
        if (g + 2 < ngroups) {
#pragma unroll
          for (int k = 0; k < PD; k++) {  // issue g+2 -> A
            const int local = ((g + 2) * PD + k) * SPLIT + sub;
            int s = __shfl(cv, local & 63);
            if (local >= m) s = n;
            aA[k] = asrc[s * H + myh];
            hA[k] = *(const uint4*)&hfeat[(size_t)s * DOUT + c0];
          }
        }
#pragma unroll
        for (int k = 0; k < PD; k++) {  // consume g+1 (B)
          const int local = ((g + 1) * PD + k) * SPLIT + sub;
          float e = aB[k] + my_adl;
          e = (e > 0.f) ? e : 0.2f * e;
          float p = __expf(e);
          p = (local < m) ? p : 0.f;
          psum += p;
          const __half2 pp = __float2half2_rn(p);
          acc2[0] = __hfma2(__builtin_bit_cast(__half2, hB[k].x), pp, acc2[0]);
          acc2[1] = __hfma2(__builtin_bit_cast(__half2, hB[k].y), pp, acc2[1]);
          acc2[2] = __hfma2(__builtin_bit_cast(__half2, hB[k].z), pp, acc2[2]);
          acc2[3] = __hfma2(__builtin_bit_cast(__half2, hB[k].w), pp, acc2[3]);
        }
      }
    }
    // flush f16 chunk accumulators to fp32
#pragma unroll
    for (int i = 0; i < 4; i++) {
      acc[2 * i] += __low2float(acc2[i]);
      acc[2 * i + 1] += __high2float(acc2[i]);
    }
  }

  // combine SPLIT sub-wave partials
#pragma unroll
  for (int o = RL; o < 64; o <<= 1) {
    psum += __shfl_xor(psum, o);
#pragma unroll
    for (int i = 0; i < 8; i++) acc[i] += __shfl_xor(acc[i], o);
  }

  const float rs = 1.f / (psum + 1e-16f);
  const float4 bi0 = *(const float4*)&bias[c0];
  const float4 bi1 = *(const float4*)&bias[c0 + 4];
  float v[8];
  v[0] = acc[0] * rs + bi0.x; v[1] = acc[1] * rs + bi0.y;
  v[2] = acc[2] * rs + bi0.z; v[3] = acc[3] * rs + bi0.w;
  v[4] = acc[4] * rs + bi1.x; v[5] = acc[5] * rs + bi1.y;
  v[6] = acc[6] * rs + bi1.z; v[7] = acc[7] * rs + bi1.w;

  float s8 = 0.f;
#pragma unroll
  for (int i = 0; i < 8; i++) s8 += v[i];
  const float mean = wave_sum(s8) / (float)(DOUT * SPLIT);
  float q8 = 0.f;
#pragma unroll
  for (int i = 0; i < 8; i++) {
    v[i] -= mean;
    q8 += v[i] * v[i];
  }
  const float var = wave_sum(q8) / (float)(DOUT * SPLIT);
  const float rstd = rsqrtf(var + 1e-5f);

  const float4 ga0 = *(const float4*)&gamma[c0];
  const float4 ga1 = *(const float4*)&gamma[c0 + 4];
  const float4 be0 = *(const float4*)&beta[c0];
  const float4 be1 = *(const float4*)&beta[c0 + 4];
  const uint4 pr = *(const uint4*)&proj[(size_t)n * DOUT + c0];
  float o0 = v[0] * rstd * ga0.x + be0.x + hlo(pr.x);
  float o1 = v[1] * rstd * ga0.y + be0.y + hhi(pr.x);
  float o2 = v[2] * rstd * ga0.z + be0.z + hlo(pr.y);
  float o3 = v[3] * rstd * ga0.w + be0.w + hhi(pr.y);
  float o4 = v[4] * rstd * ga1.x + be1.x + hlo(pr.z);
  float o5 = v[5] * rstd * ga1.y + be1.y + hhi(pr.z);
  float o6 = v[6] * rstd * ga1.z + be1.z + hlo(pr.w);
  float o7 = v[7] * rstd * ga1.w + be1.w + hhi(pr.w);
  o0 = (o0 > 0.f) ? o0 : expm1f(o0);
  o1 = (o1 > 0.f) ? o1 : expm1f(o1);
  o2 = (o2 > 0.f) ? o2 : expm1f(o2);
  o3 = (o3 > 0.f) ? o3 : expm1f(o3);
  o4 = (o4 > 0.f) ? o4 : expm1f(o4);
  o5 = (o5 > 0.f) ? o5 : expm1f(o5);
  o6 = (o6 > 0.f) ? o6 : expm1f(o6);
  o7 = (o7 > 0.f) ? o7 : expm1f(o7);
  if (sub == 0) {
    uint4 ov;
    ov.x = (unsigned int)f2h(o0) | ((unsigned int)f2h(o1) << 16);
    ov.y = (unsigned int)f2h(o2) | ((unsigned int)f2h(o3) << 16);
    ov.z = (unsigned int)f2h(o4) | ((unsigned int)f2h(o5) << 16);
    ov.w = (unsigned int)f2h(o6) | ((unsigned int)f2h(o7) << 16);
    *(uint4*)&out[(size_t)n * DOUT + c0] = ov;
  }
}

// ---------------------------------------------------------------------------
// CSR build
__global__ void hist_kernel(const int* __restrict__ dst, int* __restrict__ cnt, int E) {
  const int e = blockIdx.x * 256 + threadIdx.x;
  if (e < E) atomicAdd(&cnt[dst[e]], 1);
}

__global__ __launch_bounds__(256) void scan1_kernel(int* __restrict__ cnt,
                                                    int* __restrict__ sums, int N) {
  __shared__ int sm[256];
  const int i = blockIdx.x * 256 + threadIdx.x;
  const int v = (i < N) ? cnt[i] : 0;
  sm[threadIdx.x] = v;
  __syncthreads();
  for (int off = 1; off < 256; off <<= 1) {
    const int t = (threadIdx.x >= off) ? sm[threadIdx.x - off] : 0;
    __syncthreads();
    sm[threadIdx.x] += t;
    __syncthreads();
  }
  if (i < N) cnt[i] = sm[threadIdx.x] - v;  // exclusive within block
  if (threadIdx.x == 255) sums[blockIdx.x] = sm[255];
}

__global__ __launch_bounds__(256) void scan2_kernel(int* __restrict__ sums, int nb) {
  __shared__ int sm[256];
  const int v = (threadIdx.x < nb) ? sums[threadIdx.x] : 0;
  sm[threadIdx.x] = v;
  __syncthreads();
  for (int off = 1; off < 256; off <<= 1) {
    const int t = (threadIdx.x >= off) ? sm[threadIdx.x - off] : 0;
    __syncthreads();
    sm[threadIdx.x] += t;
    __syncthreads();
  }
  if (threadIdx.x < nb) sums[threadIdx.x] = sm[threadIdx.x] - v;  // exclusive
}

__global__ void scan3_kernel(const int* __restrict__ cnt, const int* __restrict__ sums,
                             int* __restrict__ rowptr, int* __restrict__ cursor,
                             int N, int E) {
  const int i = blockIdx.x * 256 + threadIdx.x;
  if (i < N) {
    const int r = cnt[i] + sums[blockIdx.x];
    rowptr[i] = r;
    cursor[i] = r;
  }
  if (i == 0) rowptr[N] = E;
}

__global__ void scatter_kernel(const int* __restrict__ src, const int* __restrict__ dst,
                               int* __restrict__ cursor, int* __restrict__ col, int E) {
  const int e = blockIdx.x * 256 + threadIdx.x;
  if (e < E) {
    const int p = atomicAdd(&cursor[dst[e]], 1);
    col[p] = src[e];
  }
}

// ---------------------------------------------------------------------------
// Global mean pool per graph (batch sorted): one block per graph.
__global__ __launch_bounds__(128) void pool_kernel(const unsigned short* __restrict__ h3,
                                                   const int* __restrict__ batch,
                                                   float* __restrict__ out, int N) {
  __shared__ int sse[2];
  const int g = blockIdx.x;
  if (threadIdx.x == 0) {
    int lo = 0, hi = N;
    while (lo < hi) { const int mid = (lo + hi) >> 1; if (batch[mid] < g) lo = mid + 1; else hi = mid; }
    sse[0] = lo;
    lo = 0; hi = N;
    while (lo < hi) { const int mid = (lo + hi) >> 1; if (batch[mid] < g + 1) lo = mid + 1; else hi = mid; }
    sse[1] = lo;
  }
  __syncthreads();
  const int s = sse[0], e = sse[1];
  float sum = 0.f;
  for (int r = s; r < e; r++) sum += h2f(h3[(size_t)r * 128 + threadIdx.x]);
  out[g * 128 + threadIdx.x] = (e > s) ? sum / (float)(e - s) : 0.f;
}

// ---------------------------------------------------------------------------
extern "C" void kernel_launch(void* const* d_in, const int* in_sizes, int n_in,
                              void* d_out, int out_size, void* d_ws, size_t ws_size,
                              hipStream_t stream) {
  const float* x      = (const float*)d_in[0];
  const int* edge_idx = (const int*)d_in[1];
  const int* batch    = (const int*)d_in[2];
  const float* W1     = (const float*)d_in[3];
  const float* a_src1 = (const float*)d_in[4];
  const float* a_dst1 = (const float*)d_in[5];
  const float* b1     = (const float*)d_in[6];
  const float* g1     = (const float*)d_in[7];
  const float* be1    = (const float*)d_in[8];
  const float* pw1    = (const float*)d_in[9];
  const float* pb1    = (const float*)d_in[10];
  const float* W2     = (const float*)d_in[11];
  const float* a_src2 = (const float*)d_in[12];
  const float* a_dst2 = (const float*)d_in[13];
  const float* b2     = (const float*)d_in[14];
  const float* g2     = (const float*)d_in[15];
  const float* be2    = (const float*)d_in[16];
  const float* pw2    = (const float*)d_in[17];
  const float* pb2    = (const float*)d_in[18];
  const float* W3     = (const float*)d_in[19];
  const float* a_src3 = (const float*)d_in[20];
  const float* a_dst3 = (const float*)d_in[21];
  const float* b3     = (const float*)d_in[22];
  const float* g3     = (const float*)d_in[23];
  const float* be3    = (const float*)d_in[24];
  const float* pw3    = (const float*)d_in[25];
  const float* pb3    = (const float*)d_in[26];

  const int NN = in_sizes[0] / 128;  // 50000
  const int E  = in_sizes[1] / 2;    // 800000
  const int G  = out_size / 128;     // 512
  const int M64 = (NN + 63) & ~63;   // 50048

  size_t off = 0;
  auto alloc = [&](size_t bytes) {
    size_t r = off;
    off += (bytes + 255) & ~(size_t)255;
    return r;
  };
  char* ws = (char*)d_ws;
  unsigned short* big0 = (unsigned short*)(ws + alloc((size_t)M64 * 256 * 2));  // h1feat / h3feat
  unsigned short* big1 = (unsigned short*)(ws + alloc((size_t)M64 * 256 * 2));  // h1out
  unsigned short* s0   = (unsigned short*)(ws + alloc((size_t)M64 * 128 * 2));  // xh / h2feat / h3out
  unsigned short* s1   = (unsigned short*)(ws + alloc((size_t)M64 * 128 * 2));  // h2out
  unsigned short* projb = (unsigned short*)(ws + alloc((size_t)M64 * 256 * 2)); // f16 residual
  float* asrcB = (float*)(ws + alloc((size_t)M64 * 8 * 4));
  float* adstB = (float*)(ws + alloc((size_t)M64 * 8 * 4));
  int* rowptr  = (int*)(ws + alloc((size_t)(NN + 1) * 4));
  int* cnt     = (int*)(ws + alloc((size_t)NN * 4));
  int* cursor  = (int*)(ws + alloc((size_t)NN * 4));
  int* colb    = (int*)(ws + alloc((size_t)E * 4));
  int* sums    = (int*)(ws + alloc(256 * 4));
  unsigned short* BpW1 = (unsigned short*)(ws + alloc(128 * 256 * 2));
  unsigned short* BpP1 = (unsigned short*)(ws + alloc(128 * 256 * 2));
  unsigned short* BpW2 = (unsigned short*)(ws + alloc(256 * 128 * 2));
  unsigned short* BpP2 = (unsigned short*)(ws + alloc(256 * 128 * 2));
  unsigned short* BpW3 = (unsigned short*)(ws + alloc(128 * 128 * 2));
  unsigned short* BpP3 = (unsigned short*)(ws + alloc(128 * 128 * 2));
  (void)ws_size; (void)n_in;

  const int EB = (E + 255) / 256;
  const int NB = (NN + 255) / 256;  // 196
  const int NW = (NN + 3) / 4;
  const int MB = M64 / 64;
  const int pad = M64 - NN;

  // ---- CSR build (dst-sorted adjacency), reused by all 3 layers ----
  hipMemsetAsync(cnt, 0, (size_t)NN * 4, stream);
  hist_kernel<<<EB, 256, 0, stream>>>(edge_idx + E, cnt, E);
  scan1_kernel<<<NB, 256, 0, stream>>>(cnt, sums, NN);
  scan2_kernel<<<1, 256, 0, stream>>>(sums, NB);
  scan3_kernel<<<NB, 256, 0, stream>>>(cnt, sums, rowptr, cursor, NN, E);
  scatter_kernel<<<EB, 256, 0, stream>>>(edge_idx, edge_idx + E, cursor, colb, E);

  // ---- f16 cast of x (with pad-row zeroing) + agg-out pad zeroing ----
  cast_f16_kernel<<<(M64 * 128 / 4 + 255) / 256, 256, 0, stream>>>(x, s0, NN * 32, pad * 32);
  if (pad)
    zero_pads_kernel<<<(pad * 256 + 255) / 256, 256, 0, stream>>>(
        big1 + (size_t)NN * 256, s1 + (size_t)NN * 128, pad);

  // ---- weight repacks (one kernel, 20480 threads) ----
  repack_all_kernel<<<80, 256, 0, stream>>>(W1, pw1, W2, pw2, W3, pw3,
                                            BpW1, BpP1, BpW2, BpP2, BpW3, BpP3);

  // ---- Layer 1: 128 -> 8x32 = 256 ----
  fused_gemm_kernel<128, 32, 8, false><<<dim3(4, MB), 256, 0, stream>>>(
      s0, BpW1, BpP1, pb1, a_src1, a_dst1, big0, projb, asrcB, adstB, 256);
  gat_agg_kernel<8, 32, 2><<<NW, 256, 0, stream>>>(big0, asrcB, adstB, rowptr, colb,
                                                   b1, g1, be1, projb, big1, NN);
  // big1 = h1 (f16)

  // ---- Layer 2: 256 -> 4x32 = 128 ----
  fused_gemm_kernel<256, 32, 4, false><<<dim3(2, MB), 256, 0, stream>>>(
      big1, BpW2, BpP2, pb2, a_src2, a_dst2, s0, projb, asrcB, adstB, 128);
  gat_agg_kernel<4, 32, 4><<<NW, 256, 0, stream>>>(s0, asrcB, adstB, rowptr, colb,
                                                   b2, g2, be2, projb, s1, NN);
  // s1 = h2 (f16)

  // ---- Layer 3: 128 -> 1x128 (concat=False; 1 head -> identity mean) ----
  zero2_kernel<<<(M64 + 255) / 256, 256, 0, stream>>>(asrcB, adstB, M64);
  fused_gemm_kernel<128, 128, 1, true><<<dim3(2, MB), 256, 0, stream>>>(
      s1, BpW3, BpP3, pb3, a_src3, a_dst3, big0, projb, asrcB, adstB, 128);
  gat_agg_kernel<1, 128, 4><<<NW, 256, 0, stream>>>(big0, asrcB, adstB, rowptr, colb,
                                                    b3, g3, be3, projb, s0, NN);
  // s0 = h3 (f16)

  // ---- Global mean pool per graph ----
  pool_kernel<<<G, 128, 0, stream>>>(s0, batch, (float*)d_out, NN);
}